// Round 7
// baseline (369.571 us; speedup 1.0000x reference)
//
#include <hip/hip_runtime.h>
#include <math.h>

typedef unsigned int u32;
typedef unsigned short u16;
typedef unsigned long long u64;
typedef __attribute__((ext_vector_type(8))) __bf16 bf8;
typedef __attribute__((ext_vector_type(4))) float f4;

#define MFMA(a,b,c) __builtin_amdgcn_mfma_f32_16x16x32_bf16(a,b,c,0,0,0)

// chunk swizzle for 128-row [row][40u16] tiles (xin/gates/out/attn kernels)
#define SWC(row_, c_) ((((((c_)>>1) ^ (((row_)>>3)&1))<<1) | (((c_)&1) ^ (((row_)>>4)&1))))

static __device__ __forceinline__ u32 cvtpk(float lo, float hi) {
  u32 r; asm("v_cvt_pk_bf16_f32 %0, %1, %2" : "=v"(r) : "v"(lo), "v"(hi));
  return r;
}
static __device__ __forceinline__ u16 f2b(float x) { return (u16)cvtpk(x, 0.f); }
static __device__ __forceinline__ float sigm(float x) { return 1.f/(1.f+__expf(-x)); }

// All [256ch][P] bf16 intermediates PAIR-INTERLEAVED: u32 pair q at q*P+p.
// Exception: vbuf plain [256][1156].

// ---------------- combined weight transforms (1 launch) ----------------
__global__ __launch_bounds__(256) void k_prep(const float* __restrict__ w_in,
        const float* __restrict__ w_out,
        const float* __restrict__ wqx, const float* __restrict__ wkx,
        const float* __restrict__ wvx,
        const float* __restrict__ w_ga, const float* __restrict__ w_gx,
        u16* __restrict__ winb, u16* __restrict__ woutb,
        u16* __restrict__ tq, u16* __restrict__ tk, u16* __restrict__ tv,
        u16* __restrict__ wg) {
  int task = blockIdx.y;
  int i = blockIdx.x*256 + threadIdx.x;
  if (task == 0) {
    if (i < 32768) winb[i] = f2b(w_in[i]);
    else if (i < 98304) woutb[i - 32768] = f2b(w_out[i - 32768]);
  } else if (task <= 3) {
    if (i < 589824) {
      const float* w = (task==1)?wqx:(task==2)?wkx:wvx;
      u16* wt = (task==1)?tq:(task==2)?tk:tv;
      int tap = i >> 16, mm = (i & 65535) >> 8, rr = i & 255;
      wt[i] = f2b(w[(size_t)mm*2304 + rr*9 + tap]);
    }
  } else {
    if (i < 393216) {
      int g = i >> 17, rem = i & 131071, rr = rem >> 9, kk = rem & 511;
      int gb = (g == 0) ? 0 : (g == 1) ? 512 : 768;
      float v = (kk < 256) ? w_ga[(size_t)(gb+rr)*256 + kk]
                           : w_gx[(size_t)(gb+rr)*256 + kk - 256];
      wg[i] = f2b(v);
    }
  }
}

// ---------------- xin GEMM: M=256,K=128 over x fp32 -> pair-interleaved bf16 ----
__global__ __launch_bounds__(256,2) void k_xin(const float* __restrict__ x,
        const u16* __restrict__ wb, const float* __restrict__ bias,
        u16* __restrict__ out) {
  __shared__ alignas(16) u16 Xs[128][40];
  __shared__ alignas(16) u16 Ws[128][40];
  int tid = threadIdx.x, lane = tid & 63, wid = tid >> 6;
  int li = lane & 15, gr = lane >> 4;
  int p0 = blockIdx.x*128, m0 = blockIdx.y*128, n = blockIdx.z;
  int pcol = tid & 127, rg = tid >> 7;
  int wrow = tid >> 1, wh = tid & 1;
  int p = p0 + pcol;
  const float* src = x + (size_t)n*128*1296;
  const u32* wb32 = (const u32*)wb;
  f4 z = {0.f,0.f,0.f,0.f};
  f4 acc[4][4];
  #pragma unroll
  for (int i=0;i<4;i++) { acc[i][0]=z; acc[i][1]=z; acc[i][2]=z; acc[i][3]=z; }
  int wm = (wid & 1)*64, wp = (wid >> 1)*64;
  for (int k0 = 0; k0 < 128; k0 += 32) {
    u32 rx[8];
    #pragma unroll
    for (int j = 0; j < 8; j++) {
      int rp = rg*8 + j;
      float a = 0.f, b = 0.f;
      if (p < 1296) { a = src[(size_t)(k0+2*rp)*1296+p]; b = src[(size_t)(k0+2*rp+1)*1296+p]; }
      rx[j] = cvtpk(a, b);
    }
    const u32* wsrc = wb32 + (size_t)(m0+wrow)*64 + (k0>>1) + wh*8;
    int4 rwA = *(const int4*)wsrc, rwB = *(const int4*)(wsrc+4);
    *(int4*)&Xs[pcol][SWC(pcol,2*rg)*8]   = *(int4*)&rx[0];
    *(int4*)&Xs[pcol][SWC(pcol,2*rg+1)*8] = *(int4*)&rx[4];
    *(int4*)&Ws[wrow][SWC(wrow,2*wh)*8]   = rwA;
    *(int4*)&Ws[wrow][SWC(wrow,2*wh+1)*8] = rwB;
    __syncthreads();
    bf8 af[4], bx[4];
    #pragma unroll
    for (int mt=0;mt<4;mt++) { int r = wm+mt*16+li; af[mt] = *(bf8*)&Ws[r][SWC(r,gr)*8]; }
    #pragma unroll
    for (int pt=0;pt<4;pt++) { int r = wp+pt*16+li; bx[pt] = *(bf8*)&Xs[r][SWC(r,gr)*8]; }
    #pragma unroll
    for (int mt=0;mt<4;mt++)
      #pragma unroll
      for (int pt=0;pt<4;pt++)
        acc[mt][pt] = MFMA(af[mt], bx[pt], acc[mt][pt]);
    __syncthreads();
  }
  u32* out32 = (u32*)out + (size_t)n*128*1296;
  #pragma unroll
  for (int mt=0;mt<4;mt++)
    #pragma unroll
    for (int pt=0;pt<4;pt++) {
      int mb = m0 + wm + mt*16 + gr*4;
      int pp = p0 + wp + pt*16 + li;
      if (pp < 1296) {
        out32[(size_t)(mb>>1)*1296 + pp] = cvtpk(acc[mt][pt][0]+bias[mb], acc[mt][pt][1]+bias[mb+1]);
        out32[(size_t)((mb>>1)+1)*1296 + pp] = cvtpk(acc[mt][pt][2]+bias[mb+2], acc[mt][pt][3]+bias[mb+3]);
      }
    }
}

// ------- fused q/k/v 3x3 convs: 1-WAVE blocks, 64x64 tile, NO barriers -------
// grid (59 tiles: 21 q + 19 k + 19 v, 4 m-tiles, 8 n), 64 threads.
// LDS chunk swizzle: data chunk c of row r at slot c ^ ((r>>1)&3).
__global__ __launch_bounds__(64,2) void k_conv3(const u16* __restrict__ xin,
        const u16* __restrict__ wq, const u16* __restrict__ wk, const u16* __restrict__ wv,
        u16* __restrict__ qb, u16* __restrict__ kb, u16* __restrict__ vb) {
  __shared__ alignas(16) u16 Xs[2][64][32];
  __shared__ alignas(16) u16 Wsh[2][64][32];
  int lane = threadIdx.x;
  int li = lane & 15, gr = lane >> 4;
  int tile = blockIdx.x, m0 = blockIdx.y*64, n = blockIdx.z;
  int kind, t0;
  if (tile < 21)      { kind = 0; t0 = tile; }
  else if (tile < 40) { kind = 1; t0 = tile - 21; }
  else                { kind = 2; t0 = tile - 40; }
  int P  = kind ? 1156 : 1296;
  int WO = kind ? 34 : 36;
  int p0 = t0*64;
  const u16* wt = (kind==0) ? wq : (kind==1) ? wk : wv;
  const u32* src32 = (const u32*)xin + (size_t)n*128*1296;
  const u32* wt32 = (const u32*)wt;
  int p = p0 + lane;
  bool pvld = p < P;
  int py = 0, px = 0;
  if (pvld) { py = p / WO; px = p % WO; }
  int fx = (lane >> 1) & 3;      // write swizzle (own row = lane)
  int fr = (li >> 1) & 3;        // read swizzle (rows = *16 + li)
  f4 z = {0.f,0.f,0.f,0.f};
  f4 acc[4][4];
  #pragma unroll
  for (int i=0;i<4;i++) { acc[i][0]=z; acc[i][1]=z; acc[i][2]=z; acc[i][3]=z; }
  u32 rxA[16], rxB[16];
  int4 rwA[4], rwB[4];

  #define LOADIT(it_, RX, RW) { \
    int tap_ = (it_) >> 3, r0h_ = ((it_) & 7)*16; \
    int sy = py + tap_/3 - (kind==0 ? 1 : 0); \
    int sx = px + tap_%3 - (kind==0 ? 1 : 0); \
    bool ok = pvld && sy >= 0 && sy < 36 && sx >= 0 && sx < 36; \
    const u32* xs = src32 + (size_t)r0h_*1296 + sy*36 + sx; \
    _Pragma("unroll") \
    for (int j = 0; j < 16; j++) RX[j] = ok ? xs[(size_t)j*1296] : 0u; \
    const int4* wsrc = (const int4*)(wt32 + ((size_t)(tap_*256 + m0 + lane))*128 + r0h_); \
    _Pragma("unroll") \
    for (int c = 0; c < 4; c++) RW[c] = wsrc[c]; }

  #define WRITEIT(RX, RW, b_) { \
    _Pragma("unroll") \
    for (int c = 0; c < 4; c++) { \
      *(int4*)&Xs[b_][lane][(c ^ fx)*8] = *(int4*)&RX[c*4]; \
      *(int4*)&Wsh[b_][lane][(c ^ fx)*8] = RW[c]; \
    } }

  #define MFMAIT(b_) { \
    bf8 af[4], bx[4]; \
    _Pragma("unroll") \
    for (int mt=0;mt<4;mt++) af[mt] = *(bf8*)&Wsh[b_][mt*16+li][(gr ^ fr)*8]; \
    _Pragma("unroll") \
    for (int pt=0;pt<4;pt++) bx[pt] = *(bf8*)&Xs[b_][pt*16+li][(gr ^ fr)*8]; \
    _Pragma("unroll") \
    for (int mt=0;mt<4;mt++) \
      _Pragma("unroll") \
      for (int pt=0;pt<4;pt++) \
        acc[mt][pt] = MFMA(af[mt], bx[pt], acc[mt][pt]); }

  LOADIT(0, rxA, rwA);
  WRITEIT(rxA, rwA, 0);
  LOADIT(1, rxB, rwB);
  for (int h = 0; h < 35; h++) {
    LOADIT(2*h+2, rxA, rwA);   // issue ~2 phases ahead
    MFMAIT(0);                 // tile 2h
    WRITEIT(rxB, rwB, 1);      // tile 2h+1 -> LDS1
    LOADIT(2*h+3, rxB, rwB);
    MFMAIT(1);                 // tile 2h+1
    WRITEIT(rxA, rwA, 0);      // tile 2h+2 -> LDS0
  }
  MFMAIT(0);                   // tile 70
  WRITEIT(rxB, rwB, 1);
  MFMAIT(1);                   // tile 71
  #undef LOADIT
  #undef WRITEIT
  #undef MFMAIT

  if (kind <= 1) {
    u32* dst32 = (u32*)(kind==0 ? qb : kb) + (size_t)n*128*P;
    #pragma unroll
    for (int mt=0;mt<4;mt++)
      #pragma unroll
      for (int pt=0;pt<4;pt++) {
        int mb = m0 + mt*16 + gr*4;
        int pp = p0 + pt*16 + li;
        if (pp < P) {
          dst32[(size_t)(mb>>1)*P + pp] = cvtpk(acc[mt][pt][0], acc[mt][pt][1]);
          dst32[(size_t)((mb>>1)+1)*P + pp] = cvtpk(acc[mt][pt][2], acc[mt][pt][3]);
        }
      }
  } else {
    #pragma unroll
    for (int mt=0;mt<4;mt++)
      #pragma unroll
      for (int pt=0;pt<4;pt++) {
        int pp = p0 + pt*16 + li;
        if (pp < P) {
          #pragma unroll
          for (int j=0;j<4;j++) {
            int m = m0 + mt*16 + gr*4 + j;
            vb[((size_t)n*256 + m)*1156 + pp] = f2b(acc[mt][pt][j]);
          }
        }
      }
  }
}

// ---------------- flash attention, MFMA, online softmax (defer-max) ----------------
__global__ __launch_bounds__(256,2) void k_attn(const u16* __restrict__ qbf,
        const u16* __restrict__ kbf, const u16* __restrict__ vbf, u16* __restrict__ abf) {
  __shared__ alignas(16) u16 Qs[128][40];
  __shared__ alignas(16) u16 Ks[64][40];
  __shared__ alignas(16) u16 Vs[2][32][40];
  __shared__ alignas(16) u16 Ps[4][2][32][40];
  int tid = threadIdx.x, lane = tid & 63, wid = tid >> 6;
  int li = lane & 15, gr = lane >> 4;
  int h = blockIdx.y, n = blockIdx.z;
  int q0 = blockIdx.x*128;
  const u32* Qp32 = (const u32*)qbf + ((size_t)n*128 + h*16)*1296;
  const u32* Kp32 = (const u32*)kbf + ((size_t)n*128 + h*16)*1156;
  const u16* Vp = vbf + ((size_t)n*256 + h*32)*1156;
  #pragma unroll
  for (int j = 0; j < 8; j++) {
    int idx = tid + j*256, qq = idx >> 4, cp = idx & 15;
    int gq = q0 + qq;
    ((u32*)&Qs[qq][0])[cp] = (gq < 1296) ? Qp32[(size_t)cp*1296 + gq] : 0u;
  }
  f4 z = {0.f,0.f,0.f,0.f};
  float mx[2] = {-1e30f, -1e30f}, ls[2] = {0.f, 0.f};
  f4 accO[2][2] = {{z,z},{z,z}};
  int wq = wid*32;
  int kdd = tid >> 2, kq = tid & 3;
  __syncthreads();
  for (int d0 = 0; d0 < 1156; d0 += 64) {
    {
      u32 kk[4];
      int gd = d0 + kdd;
      #pragma unroll
      for (int i = 0; i < 4; i++)
        kk[i] = (gd < 1156) ? Kp32[(size_t)(kq*4+i)*1156 + gd] : 0u;
      *(int4*)&Ks[kdd][SWC(kdd,kq)*8] = *(int4*)&kk[0];
    }
    #pragma unroll
    for (int j = 0; j < 4; j++) {
      int idx = tid + j*256, half = idx >> 9, rem = idx & 511;
      int cc = rem >> 4, dp = rem & 15;
      int gd = d0 + half*32 + dp*2; u32 v = 0;
      if (gd < 1156) v = *(const u32*)&Vp[(size_t)cc*1156 + gd];
      ((u32*)&Vs[half][cc][0])[dp] = v;
    }
    __syncthreads();
    bf8 ak[4], bq[2];
    #pragma unroll
    for (int dt=0;dt<4;dt++) { int r = dt*16+li; ak[dt] = *(bf8*)&Ks[r][SWC(r,gr)*8]; }
    #pragma unroll
    for (int qt=0;qt<2;qt++) bq[qt] = *(bf8*)&Qs[wq + qt*16 + li][8*gr];
    f4 s[2][4];
    #pragma unroll
    for (int qt=0;qt<2;qt++)
      #pragma unroll
      for (int dt=0;dt<4;dt++)
        s[qt][dt] = MFMA(ak[dt], bq[qt], z);
    bool tail = (d0 + 64 > 1156);
    #pragma unroll
    for (int qt=0;qt<2;qt++) {
      if (tail) {
        #pragma unroll
        for (int dt=0;dt<4;dt++)
          #pragma unroll
          for (int j=0;j<4;j++)
            if (d0 + dt*16 + gr*4 + j >= 1156) s[qt][dt][j] = -1e30f;
      }
      float tm = -1e30f;
      #pragma unroll
      for (int dt=0;dt<4;dt++)
        #pragma unroll
        for (int j=0;j<4;j++) tm = fmaxf(tm, s[qt][dt][j]);
      tm = fmaxf(tm, __shfl_xor(tm, 16));
      tm = fmaxf(tm, __shfl_xor(tm, 32));
      if (__any(tm > mx[qt] + 8.f)) {
        float nm = fmaxf(mx[qt], tm);
        float corr = __expf(mx[qt] - nm);
        mx[qt] = nm;
        ls[qt] *= corr;
        accO[0][qt] *= corr; accO[1][qt] *= corr;
      }
      float rs = 0.f;
      #pragma unroll
      for (int dt=0;dt<4;dt++)
        #pragma unroll
        for (int j=0;j<4;j++) {
          float e = __expf(s[qt][dt][j] - mx[qt]);
          s[qt][dt][j] = e; rs += e;
        }
      rs += __shfl_xor(rs, 16); rs += __shfl_xor(rs, 32);
      ls[qt] += rs;
      #pragma unroll
      for (int dt=0;dt<4;dt++) {
        u32 lo_ = cvtpk(s[qt][dt][0], s[qt][dt][1]);
        u32 hi_ = cvtpk(s[qt][dt][2], s[qt][dt][3]);
        u64 pk = (u64)lo_ | ((u64)hi_ << 32);
        *(u64*)&Ps[wid][dt>>1][qt*16 + li][(dt&1)*16 + gr*4] = pk;
      }
    }
    #pragma unroll
    for (int kt=0;kt<2;kt++) {
      bf8 av0 = *(bf8*)&Vs[kt][li][8*gr];
      bf8 av1 = *(bf8*)&Vs[kt][16 + li][8*gr];
      bf8 bp0 = *(bf8*)&Ps[wid][kt][li][8*gr];
      bf8 bp1 = *(bf8*)&Ps[wid][kt][16 + li][8*gr];
      accO[0][0] = MFMA(av0, bp0, accO[0][0]);
      accO[0][1] = MFMA(av0, bp1, accO[0][1]);
      accO[1][0] = MFMA(av1, bp0, accO[1][0]);
      accO[1][1] = MFMA(av1, bp1, accO[1][1]);
    }
    __syncthreads();
  }
  u32* ab32 = (u32*)abf + (size_t)n*128*1296;
  #pragma unroll
  for (int qt=0;qt<2;qt++) {
    float inv = 1.f / ls[qt];
    #pragma unroll
    for (int mt=0;mt<2;mt++) {
      int cb = h*32 + mt*16 + gr*4;
      int gq = q0 + wq + qt*16 + li;
      if (gq < 1296) {
        ab32[(size_t)(cb>>1)*1296 + gq] = cvtpk(accO[mt][qt][0]*inv, accO[mt][qt][1]*inv);
        ab32[(size_t)((cb>>1)+1)*1296 + gq] = cvtpk(accO[mt][qt][2]*inv, accO[mt][qt][3]*inv);
      }
    }
  }
}

// ---------------- fused gates GEMM (i,g,o; K=512) + LSTM nonlinearity ----------------
__global__ __launch_bounds__(256,2) void k_gates(const u16* __restrict__ abf,
        const u16* __restrict__ xin, const u16* __restrict__ wg,
        const float* __restrict__ b_g, u16* __restrict__ hn) {
  __shared__ alignas(16) u16 Xs[128][40];
  __shared__ alignas(16) u16 Wg[3][64][40];
  int tid = threadIdx.x, lane = tid & 63, wid = tid >> 6;
  int li = lane & 15, gr = lane >> 4;
  int p0 = blockIdx.x*128, m0 = blockIdx.y*64, n = blockIdx.z;
  int pcol = tid & 127, rg = tid >> 7;
  int p = p0 + pcol;
  const u32* wg32 = (const u32*)wg;
  f4 z = {0.f,0.f,0.f,0.f};
  f4 acc[3][2][4];
  #pragma unroll
  for (int g=0;g<3;g++)
    #pragma unroll
    for (int mt=0;mt<2;mt++) { acc[g][mt][0]=z; acc[g][mt][1]=z; acc[g][mt][2]=z; acc[g][mt][3]=z; }
  int wm = (wid & 1)*32, wp = (wid >> 1)*64;
  for (int k0 = 0; k0 < 512; k0 += 32) {
    const u32* src32 = (const u32*)((k0 < 256) ? abf : xin)
        + (size_t)n*128*1296 + (size_t)((k0 & 255)>>1)*1296;
    u32 rx[8];
    #pragma unroll
    for (int j = 0; j < 8; j++) {
      int rp = rg*8 + j;
      rx[j] = (p < 1296) ? src32[(size_t)rp*1296 + p] : 0u;
    }
    *(int4*)&Xs[pcol][SWC(pcol,2*rg)*8]   = *(int4*)&rx[0];
    *(int4*)&Xs[pcol][SWC(pcol,2*rg+1)*8] = *(int4*)&rx[4];
    #pragma unroll
    for (int j = 0; j < 3; j++) {
      int sid = tid + j*256;
      int rid = sid >> 2, q = sid & 3;
      int g = rid >> 6, mm = rid & 63;
      const u32* wsrc = wg32 + (size_t)g*65536 + (size_t)(m0+mm)*256 + (k0>>1) + q*4;
      int4 w4 = *(const int4*)wsrc;
      *(int4*)&Wg[g][mm][SWC(mm,q)*8] = w4;
    }
    __syncthreads();
    bf8 bx[4];
    #pragma unroll
    for (int pt=0;pt<4;pt++) { int r = wp+pt*16+li; bx[pt] = *(bf8*)&Xs[r][SWC(r,gr)*8]; }
    #pragma unroll
    for (int g=0;g<3;g++)
      #pragma unroll
      for (int mt=0;mt<2;mt++) {
        int r = wm+mt*16+li;
        bf8 af = *(bf8*)&Wg[g][r][SWC(r,gr)*8];
        #pragma unroll
        for (int pt=0;pt<4;pt++)
          acc[g][mt][pt] = MFMA(af, bx[pt], acc[g][mt][pt]);
      }
    __syncthreads();
  }
  u32* hn32 = (u32*)hn + (size_t)n*128*1296;
  #pragma unroll
  for (int mt=0;mt<2;mt++)
    #pragma unroll
    for (int pt=0;pt<4;pt++) {
      int rb = m0 + wm + mt*16 + gr*4;
      int pp = p0 + wp + pt*16 + li;
      if (pp < 1296) {
        float hv[4];
        #pragma unroll
        for (int j=0;j<4;j++) {
          float gi = acc[0][mt][pt][j] + b_g[rb+j];
          float gg = acc[1][mt][pt][j] + b_g[512 + rb+j];
          float go = acc[2][mt][pt][j] + b_g[768 + rb+j];
          hv[j] = sigm(go) * tanhf(sigm(gi) * tanhf(gg));
        }
        hn32[(size_t)(rb>>1)*1296 + pp] = cvtpk(hv[0], hv[1]);
        hn32[(size_t)((rb>>1)+1)*1296 + pp] = cvtpk(hv[2], hv[3]);
      }
    }
}

// ---------------- out GEMM: M=256,K=256 over hn (pair-interleaved), out fp32 -------
__global__ __launch_bounds__(256,2) void k_out(const u16* __restrict__ hn,
        const u16* __restrict__ wb, const float* __restrict__ bias,
        float* __restrict__ out) {
  __shared__ alignas(16) u16 Xs[128][40];
  __shared__ alignas(16) u16 Ws[128][40];
  int tid = threadIdx.x, lane = tid & 63, wid = tid >> 6;
  int li = lane & 15, gr = lane >> 4;
  int p0 = blockIdx.x*128, m0 = blockIdx.y*128, n = blockIdx.z;
  int pcol = tid & 127, rg = tid >> 7;
  int wrow = tid >> 1, wh = tid & 1;
  int p = p0 + pcol;
  const u32* src32 = (const u32*)hn + (size_t)n*128*1296;
  const u32* wb32 = (const u32*)wb;
  f4 z = {0.f,0.f,0.f,0.f};
  f4 acc[4][4];
  #pragma unroll
  for (int i=0;i<4;i++) { acc[i][0]=z; acc[i][1]=z; acc[i][2]=z; acc[i][3]=z; }
  int wm = (wid & 1)*64, wp = (wid >> 1)*64;
  for (int k0 = 0; k0 < 256; k0 += 32) {
    u32 rx[8];
    #pragma unroll
    for (int j = 0; j < 8; j++) {
      int rp = rg*8 + j;
      rx[j] = (p < 1296) ? src32[(size_t)((k0>>1) + rp)*1296 + p] : 0u;
    }
    const u32* wsrc = wb32 + (size_t)(m0+wrow)*128 + (k0>>1) + wh*8;
    int4 rwA = *(const int4*)wsrc, rwB = *(const int4*)(wsrc+4);
    *(int4*)&Xs[pcol][SWC(pcol,2*rg)*8]   = *(int4*)&rx[0];
    *(int4*)&Xs[pcol][SWC(pcol,2*rg+1)*8] = *(int4*)&rx[4];
    *(int4*)&Ws[wrow][SWC(wrow,2*wh)*8]   = rwA;
    *(int4*)&Ws[wrow][SWC(wrow,2*wh+1)*8] = rwB;
    __syncthreads();
    bf8 af[4], bx[4];
    #pragma unroll
    for (int mt=0;mt<4;mt++) { int r = wm+mt*16+li; af[mt] = *(bf8*)&Ws[r][SWC(r,gr)*8]; }
    #pragma unroll
    for (int pt=0;pt<4;pt++) { int r = wp+pt*16+li; bx[pt] = *(bf8*)&Xs[r][SWC(r,gr)*8]; }
    #pragma unroll
    for (int mt=0;mt<4;mt++)
      #pragma unroll
      for (int pt=0;pt<4;pt++)
        acc[mt][pt] = MFMA(af[mt], bx[pt], acc[mt][pt]);
    __syncthreads();
  }
  #pragma unroll
  for (int mt=0;mt<4;mt++)
    #pragma unroll
    for (int pt=0;pt<4;pt++)
      #pragma unroll
      for (int j=0;j<4;j++) {
        int m = m0 + wm + mt*16 + gr*4 + j;
        int pp = p0 + wp + pt*16 + li;
        if (pp < 1296) out[((size_t)n*256 + m)*1296 + pp] = acc[mt][pt][j] + bias[m];
      }
}

extern "C" void kernel_launch(void* const* d_in, const int* in_sizes, int n_in,
                              void* d_out, int out_size, void* d_ws, size_t ws_size,
                              hipStream_t stream) {
  const float* x     = (const float*)d_in[0];
  const float* w_in  = (const float*)d_in[1];
  const float* b_in  = (const float*)d_in[2];
  const float* w_qx  = (const float*)d_in[3];
  const float* w_kx  = (const float*)d_in[5];
  const float* w_vx  = (const float*)d_in[7];
  const float* w_ga  = (const float*)d_in[9];
  const float* b_g   = (const float*)d_in[10];
  const float* w_gx  = (const float*)d_in[11];
  const float* w_out = (const float*)d_in[13];
  const float* b_out = (const float*)d_in[14];
  float* out = (float*)d_out;

  u16* ws = (u16*)d_ws;
  size_t o = 0;
  u16* xin_bf = ws + o; o += 2654208;
  u16* qbuf   = ws + o; o += 2654208;
  u16* kbuf   = ws + o; o += 2367488;
  u16* vbuf   = ws + o; o += 2367488;
  u16* abuf   = ws + o; o += 2654208;
  u16* hnb    = ws + o; o += 2654208;
  u16* wqT    = ws + o; o += 589824;
  u16* wkT    = ws + o; o += 589824;
  u16* wvT    = ws + o; o += 589824;
  u16* wgT    = ws + o; o += 393216;
  u16* winb   = ws + o; o += 32768;
  u16* woutb  = ws + o; o += 65536;

  k_prep<<<dim3(2304,5), 256, 0, stream>>>(w_in, w_out, w_qx, w_kx, w_vx,
                                           w_ga, w_gx, winb, woutb, wqT, wkT, wvT, wgT);

  k_xin  <<<dim3(11,2,8), 256, 0, stream>>>(x, winb, b_in, xin_bf);
  k_conv3<<<dim3(59,4,8), 64, 0, stream>>>(xin_bf, wqT, wkT, wvT, qbuf, kbuf, vbuf);
  k_attn <<<dim3(11,8,8), 256, 0, stream>>>(qbuf, kbuf, vbuf, abuf);
  k_gates<<<dim3(11,4,8), 256, 0, stream>>>(abuf, xin_bf, wgT, b_g, hnb);
  k_out  <<<dim3(11,2,8), 256, 0, stream>>>(hnb, woutb, b_out, out);
}

// Round 8
// 201.445 us; speedup vs baseline: 1.8346x; 1.8346x over previous
//
#include <hip/hip_runtime.h>
#include <math.h>

typedef unsigned int u32;
typedef unsigned short u16;
typedef unsigned long long u64;
typedef __attribute__((ext_vector_type(8))) __bf16 bf8;
typedef __attribute__((ext_vector_type(4))) float f4;

#define MFMA(a,b,c) __builtin_amdgcn_mfma_f32_16x16x32_bf16(a,b,c,0,0,0)

// chunk swizzle for 128-row [row][40u16] tiles (xin/gates/out/attn kernels)
#define SWC(row_, c_) ((((((c_)>>1) ^ (((row_)>>3)&1))<<1) | (((c_)&1) ^ (((row_)>>4)&1))))

static __device__ __forceinline__ u32 cvtpk(float lo, float hi) {
  u32 r; asm("v_cvt_pk_bf16_f32 %0, %1, %2" : "=v"(r) : "v"(lo), "v"(hi));
  return r;
}
static __device__ __forceinline__ u16 f2b(float x) { return (u16)cvtpk(x, 0.f); }
static __device__ __forceinline__ float sigm(float x) { return 1.f/(1.f+__expf(-x)); }

// All [256ch][P] bf16 intermediates PAIR-INTERLEAVED: u32 pair q at q*P+p.
// Exception: vbuf plain [256][1156].
// Conv weights stored FRAGMENT-MAJOR: [72 ksteps][16 mb][4 gr][16 li] x int4,
// int4 = W[m=mb*16+li][k = (it&7)*32 + gr*8 .. +7], it = tap*8 + kg.

// ---------------- combined weight transforms (1 launch) ----------------
__global__ __launch_bounds__(256) void k_prep(const float* __restrict__ w_in,
        const float* __restrict__ w_out,
        const float* __restrict__ wqx, const float* __restrict__ wkx,
        const float* __restrict__ wvx,
        const float* __restrict__ w_ga, const float* __restrict__ w_gx,
        u16* __restrict__ winb, u16* __restrict__ woutb,
        u16* __restrict__ tq, u16* __restrict__ tk, u16* __restrict__ tv,
        u16* __restrict__ wg) {
  int task = blockIdx.y;
  int i = blockIdx.x*256 + threadIdx.x;
  if (task == 0) {
    if (i < 32768) winb[i] = f2b(w_in[i]);
    else if (i < 98304) woutb[i - 32768] = f2b(w_out[i - 32768]);
  } else if (task <= 3) {
    if (i < 589824) {
      const float* w = (task==1)?wqx:(task==2)?wkx:wvx;
      u16* wt = (task==1)?tq:(task==2)?tk:tv;
      int e = i & 7, li = (i>>3) & 15, gr = (i>>7) & 3, mb = (i>>9) & 15, it = i >> 13;
      int tap = it >> 3, kg = it & 7;
      int m = mb*16 + li, k = kg*32 + gr*8 + e;
      wt[i] = f2b(w[(size_t)m*2304 + k*9 + tap]);
    }
  } else {
    if (i < 393216) {
      int g = i >> 17, rem = i & 131071, rr = rem >> 9, kk = rem & 511;
      int gb = (g == 0) ? 0 : (g == 1) ? 512 : 768;
      float v = (kk < 256) ? w_ga[(size_t)(gb+rr)*256 + kk]
                           : w_gx[(size_t)(gb+rr)*256 + kk - 256];
      wg[i] = f2b(v);
    }
  }
}

// ---------------- xin GEMM: M=256,K=128 over x fp32 -> pair-interleaved bf16 ----
__global__ __launch_bounds__(256,2) void k_xin(const float* __restrict__ x,
        const u16* __restrict__ wb, const float* __restrict__ bias,
        u16* __restrict__ out) {
  __shared__ alignas(16) u16 Xs[128][40];
  __shared__ alignas(16) u16 Ws[128][40];
  int tid = threadIdx.x, lane = tid & 63, wid = tid >> 6;
  int li = lane & 15, gr = lane >> 4;
  int p0 = blockIdx.x*128, m0 = blockIdx.y*128, n = blockIdx.z;
  int pcol = tid & 127, rg = tid >> 7;
  int wrow = tid >> 1, wh = tid & 1;
  int p = p0 + pcol;
  const float* src = x + (size_t)n*128*1296;
  const u32* wb32 = (const u32*)wb;
  f4 z = {0.f,0.f,0.f,0.f};
  f4 acc[4][4];
  #pragma unroll
  for (int i=0;i<4;i++) { acc[i][0]=z; acc[i][1]=z; acc[i][2]=z; acc[i][3]=z; }
  int wm = (wid & 1)*64, wp = (wid >> 1)*64;
  for (int k0 = 0; k0 < 128; k0 += 32) {
    u32 rx[8];
    #pragma unroll
    for (int j = 0; j < 8; j++) {
      int rp = rg*8 + j;
      float a = 0.f, b = 0.f;
      if (p < 1296) { a = src[(size_t)(k0+2*rp)*1296+p]; b = src[(size_t)(k0+2*rp+1)*1296+p]; }
      rx[j] = cvtpk(a, b);
    }
    const u32* wsrc = wb32 + (size_t)(m0+wrow)*64 + (k0>>1) + wh*8;
    int4 rwA = *(const int4*)wsrc, rwB = *(const int4*)(wsrc+4);
    *(int4*)&Xs[pcol][SWC(pcol,2*rg)*8]   = *(int4*)&rx[0];
    *(int4*)&Xs[pcol][SWC(pcol,2*rg+1)*8] = *(int4*)&rx[4];
    *(int4*)&Ws[wrow][SWC(wrow,2*wh)*8]   = rwA;
    *(int4*)&Ws[wrow][SWC(wrow,2*wh+1)*8] = rwB;
    __syncthreads();
    bf8 af[4], bx[4];
    #pragma unroll
    for (int mt=0;mt<4;mt++) { int r = wm+mt*16+li; af[mt] = *(bf8*)&Ws[r][SWC(r,gr)*8]; }
    #pragma unroll
    for (int pt=0;pt<4;pt++) { int r = wp+pt*16+li; bx[pt] = *(bf8*)&Xs[r][SWC(r,gr)*8]; }
    #pragma unroll
    for (int mt=0;mt<4;mt++)
      #pragma unroll
      for (int pt=0;pt<4;pt++)
        acc[mt][pt] = MFMA(af[mt], bx[pt], acc[mt][pt]);
    __syncthreads();
  }
  u32* out32 = (u32*)out + (size_t)n*128*1296;
  #pragma unroll
  for (int mt=0;mt<4;mt++)
    #pragma unroll
    for (int pt=0;pt<4;pt++) {
      int mb = m0 + wm + mt*16 + gr*4;
      int pp = p0 + wp + pt*16 + li;
      if (pp < 1296) {
        out32[(size_t)(mb>>1)*1296 + pp] = cvtpk(acc[mt][pt][0]+bias[mb], acc[mt][pt][1]+bias[mb+1]);
        out32[(size_t)((mb>>1)+1)*1296 + pp] = cvtpk(acc[mt][pt][2]+bias[mb+2], acc[mt][pt][3]+bias[mb+3]);
      }
    }
}

// ------- fused q/k/v 3x3 convs: 256px x 64m tile, W in regs, ZERO barriers -------
// grid (16 tiles: 6 q + 5 k + 5 v, 4 m-quarters, 8 n), 256 threads (4 waves).
// Thread t stages pixel px0+t (16 u32); wave w reads only its own 64-px slice
// -> intra-wave lgkmcnt ordering, no s_barrier. W read as fragment-major int4.
__global__ __launch_bounds__(256,2) void k_conv3(const u16* __restrict__ xin,
        const u16* __restrict__ wq, const u16* __restrict__ wk, const u16* __restrict__ wv,
        u16* __restrict__ qb, u16* __restrict__ kb, u16* __restrict__ vb) {
  __shared__ alignas(16) u16 Xs[2][256][32];
  int tid = threadIdx.x, lane = tid & 63, wid = tid >> 6;
  int li = lane & 15, gr = lane >> 4;
  int tile = blockIdx.x, m0 = blockIdx.y*64, n = blockIdx.z;
  int kind, t0;
  if (tile < 6)       { kind = 0; t0 = tile; }
  else if (tile < 11) { kind = 1; t0 = tile - 6; }
  else                { kind = 2; t0 = tile - 11; }
  int P  = kind ? 1156 : 1296;
  int WO = kind ? 34 : 36;
  int pad = kind ? 0 : 1;
  int px0 = t0*256;
  const u16* wt = (kind==0) ? wq : (kind==1) ? wk : wv;
  const u32* src32 = (const u32*)xin + (size_t)n*128*1296;
  const int4* wt4 = (const int4*)wt;     // [72][16 mb][64 lane] int4
  int p = px0 + tid;
  bool pvld = p < P;
  int py = 0, px = 0;
  if (pvld) { py = p / WO; px = p % WO; }
  int fx = (tid >> 1) & 3;               // write swizzle (own row = tid)
  int fr = (li >> 1) & 3;                // read swizzle (row = wid*64+pt*16+li)
  int mb0 = m0 >> 4;
  f4 z = {0.f,0.f,0.f,0.f};
  f4 acc[4][4];
  #pragma unroll
  for (int i=0;i<4;i++) { acc[i][0]=z; acc[i][1]=z; acc[i][2]=z; acc[i][3]=z; }
  u32 xA[16], xB[16];
  int4 wA[4], wB[4];

  #define LOADX(it_, X) { \
    int tap_ = (it_) >> 3, kg_ = (it_) & 7; \
    int sy = py + tap_/3 - pad, sx = px + tap_%3 - pad; \
    bool ok = pvld && sy >= 0 && sy < 36 && sx >= 0 && sx < 36; \
    const u32* xs = src32 + (size_t)(kg_*16)*1296 + sy*36 + sx; \
    _Pragma("unroll") \
    for (int j = 0; j < 16; j++) X[j] = ok ? xs[(size_t)j*1296] : 0u; }

  #define LOADW(it_, W) { \
    const int4* wsrc = wt4 + ((size_t)(it_)*16 + mb0)*64 + lane; \
    _Pragma("unroll") \
    for (int mt = 0; mt < 4; mt++) W[mt] = wsrc[(size_t)mt*64]; }

  #define WRITEX(X, b_) { \
    _Pragma("unroll") \
    for (int c = 0; c < 4; c++) \
      *(int4*)&Xs[b_][tid][(c ^ fx)*8] = *(int4*)&X[c*4]; }

  #define MFMAIT(b_, W) { \
    bf8 bx[4]; \
    _Pragma("unroll") \
    for (int pt=0;pt<4;pt++) { \
      int r = wid*64 + pt*16 + li; \
      bx[pt] = *(bf8*)&Xs[b_][r][(gr ^ fr)*8]; \
    } \
    _Pragma("unroll") \
    for (int mt=0;mt<4;mt++) \
      _Pragma("unroll") \
      for (int pt=0;pt<4;pt++) \
        acc[mt][pt] = MFMA(*(bf8*)&W[mt], bx[pt], acc[mt][pt]); }

  LOADX(0, xA); LOADW(0, wA);
  WRITEX(xA, 0);
  LOADX(1, xB); LOADW(1, wB);
  for (int h = 0; h < 35; h++) {
    MFMAIT(0, wA);                 // step 2h (buf0)
    WRITEX(xB, 1);                 // step 2h+1 -> buf1
    LOADX(2*h+2, xA); LOADW(2*h+2, wA);
    MFMAIT(1, wB);                 // step 2h+1 (buf1)
    WRITEX(xA, 0);                 // step 2h+2 -> buf0
    LOADX(2*h+3, xB); LOADW(2*h+3, wB);
  }
  MFMAIT(0, wA);                   // step 70
  WRITEX(xB, 1);
  MFMAIT(1, wB);                   // step 71
  #undef LOADX
  #undef LOADW
  #undef WRITEX
  #undef MFMAIT

  if (kind <= 1) {
    u32* dst32 = (u32*)(kind==0 ? qb : kb) + (size_t)n*128*P;
    #pragma unroll
    for (int mt=0;mt<4;mt++)
      #pragma unroll
      for (int pt=0;pt<4;pt++) {
        int mb = m0 + mt*16 + gr*4;
        int pp = px0 + wid*64 + pt*16 + li;
        if (pp < P) {
          dst32[(size_t)(mb>>1)*P + pp] = cvtpk(acc[mt][pt][0], acc[mt][pt][1]);
          dst32[(size_t)((mb>>1)+1)*P + pp] = cvtpk(acc[mt][pt][2], acc[mt][pt][3]);
        }
      }
  } else {
    #pragma unroll
    for (int mt=0;mt<4;mt++)
      #pragma unroll
      for (int pt=0;pt<4;pt++) {
        int pp = px0 + wid*64 + pt*16 + li;
        if (pp < P) {
          #pragma unroll
          for (int j=0;j<4;j++) {
            int m = m0 + mt*16 + gr*4 + j;
            vb[((size_t)n*256 + m)*1156 + pp] = f2b(acc[mt][pt][j]);
          }
        }
      }
  }
}

// ---------------- flash attention, MFMA, online softmax (defer-max) ----------------
__global__ __launch_bounds__(256,2) void k_attn(const u16* __restrict__ qbf,
        const u16* __restrict__ kbf, const u16* __restrict__ vbf, u16* __restrict__ abf) {
  __shared__ alignas(16) u16 Qs[128][40];
  __shared__ alignas(16) u16 Ks[64][40];
  __shared__ alignas(16) u16 Vs[2][32][40];
  __shared__ alignas(16) u16 Ps[4][2][32][40];
  int tid = threadIdx.x, lane = tid & 63, wid = tid >> 6;
  int li = lane & 15, gr = lane >> 4;
  int h = blockIdx.y, n = blockIdx.z;
  int q0 = blockIdx.x*128;
  const u32* Qp32 = (const u32*)qbf + ((size_t)n*128 + h*16)*1296;
  const u32* Kp32 = (const u32*)kbf + ((size_t)n*128 + h*16)*1156;
  const u16* Vp = vbf + ((size_t)n*256 + h*32)*1156;
  #pragma unroll
  for (int j = 0; j < 8; j++) {
    int idx = tid + j*256, qq = idx >> 4, cp = idx & 15;
    int gq = q0 + qq;
    ((u32*)&Qs[qq][0])[cp] = (gq < 1296) ? Qp32[(size_t)cp*1296 + gq] : 0u;
  }
  f4 z = {0.f,0.f,0.f,0.f};
  float mx[2] = {-1e30f, -1e30f}, ls[2] = {0.f, 0.f};
  f4 accO[2][2] = {{z,z},{z,z}};
  int wq = wid*32;
  int kdd = tid >> 2, kq = tid & 3;
  __syncthreads();
  for (int d0 = 0; d0 < 1156; d0 += 64) {
    {
      u32 kk[4];
      int gd = d0 + kdd;
      #pragma unroll
      for (int i = 0; i < 4; i++)
        kk[i] = (gd < 1156) ? Kp32[(size_t)(kq*4+i)*1156 + gd] : 0u;
      *(int4*)&Ks[kdd][SWC(kdd,kq)*8] = *(int4*)&kk[0];
    }
    #pragma unroll
    for (int j = 0; j < 4; j++) {
      int idx = tid + j*256, half = idx >> 9, rem = idx & 511;
      int cc = rem >> 4, dp = rem & 15;
      int gd = d0 + half*32 + dp*2; u32 v = 0;
      if (gd < 1156) v = *(const u32*)&Vp[(size_t)cc*1156 + gd];
      ((u32*)&Vs[half][cc][0])[dp] = v;
    }
    __syncthreads();
    bf8 ak[4], bq[2];
    #pragma unroll
    for (int dt=0;dt<4;dt++) { int r = dt*16+li; ak[dt] = *(bf8*)&Ks[r][SWC(r,gr)*8]; }
    #pragma unroll
    for (int qt=0;qt<2;qt++) bq[qt] = *(bf8*)&Qs[wq + qt*16 + li][8*gr];
    f4 s[2][4];
    #pragma unroll
    for (int qt=0;qt<2;qt++)
      #pragma unroll
      for (int dt=0;dt<4;dt++)
        s[qt][dt] = MFMA(ak[dt], bq[qt], z);
    bool tail = (d0 + 64 > 1156);
    #pragma unroll
    for (int qt=0;qt<2;qt++) {
      if (tail) {
        #pragma unroll
        for (int dt=0;dt<4;dt++)
          #pragma unroll
          for (int j=0;j<4;j++)
            if (d0 + dt*16 + gr*4 + j >= 1156) s[qt][dt][j] = -1e30f;
      }
      float tm = -1e30f;
      #pragma unroll
      for (int dt=0;dt<4;dt++)
        #pragma unroll
        for (int j=0;j<4;j++) tm = fmaxf(tm, s[qt][dt][j]);
      tm = fmaxf(tm, __shfl_xor(tm, 16));
      tm = fmaxf(tm, __shfl_xor(tm, 32));
      if (__any(tm > mx[qt] + 8.f)) {
        float nm = fmaxf(mx[qt], tm);
        float corr = __expf(mx[qt] - nm);
        mx[qt] = nm;
        ls[qt] *= corr;
        accO[0][qt] *= corr; accO[1][qt] *= corr;
      }
      float rs = 0.f;
      #pragma unroll
      for (int dt=0;dt<4;dt++)
        #pragma unroll
        for (int j=0;j<4;j++) {
          float e = __expf(s[qt][dt][j] - mx[qt]);
          s[qt][dt][j] = e; rs += e;
        }
      rs += __shfl_xor(rs, 16); rs += __shfl_xor(rs, 32);
      ls[qt] += rs;
      #pragma unroll
      for (int dt=0;dt<4;dt++) {
        u32 lo_ = cvtpk(s[qt][dt][0], s[qt][dt][1]);
        u32 hi_ = cvtpk(s[qt][dt][2], s[qt][dt][3]);
        u64 pk = (u64)lo_ | ((u64)hi_ << 32);
        *(u64*)&Ps[wid][dt>>1][qt*16 + li][(dt&1)*16 + gr*4] = pk;
      }
    }
    #pragma unroll
    for (int kt=0;kt<2;kt++) {
      bf8 av0 = *(bf8*)&Vs[kt][li][8*gr];
      bf8 av1 = *(bf8*)&Vs[kt][16 + li][8*gr];
      bf8 bp0 = *(bf8*)&Ps[wid][kt][li][8*gr];
      bf8 bp1 = *(bf8*)&Ps[wid][kt][16 + li][8*gr];
      accO[0][0] = MFMA(av0, bp0, accO[0][0]);
      accO[0][1] = MFMA(av0, bp1, accO[0][1]);
      accO[1][0] = MFMA(av1, bp0, accO[1][0]);
      accO[1][1] = MFMA(av1, bp1, accO[1][1]);
    }
    __syncthreads();
  }
  u32* ab32 = (u32*)abf + (size_t)n*128*1296;
  #pragma unroll
  for (int qt=0;qt<2;qt++) {
    float inv = 1.f / ls[qt];
    #pragma unroll
    for (int mt=0;mt<2;mt++) {
      int cb = h*32 + mt*16 + gr*4;
      int gq = q0 + wq + qt*16 + li;
      if (gq < 1296) {
        ab32[(size_t)(cb>>1)*1296 + gq] = cvtpk(accO[mt][qt][0]*inv, accO[mt][qt][1]*inv);
        ab32[(size_t)((cb>>1)+1)*1296 + gq] = cvtpk(accO[mt][qt][2]*inv, accO[mt][qt][3]*inv);
      }
    }
  }
}

// ---------------- fused gates GEMM (i,g,o; K=512) + LSTM nonlinearity ----------------
__global__ __launch_bounds__(256,2) void k_gates(const u16* __restrict__ abf,
        const u16* __restrict__ xin, const u16* __restrict__ wg,
        const float* __restrict__ b_g, u16* __restrict__ hn) {
  __shared__ alignas(16) u16 Xs[128][40];
  __shared__ alignas(16) u16 Wg[3][64][40];
  int tid = threadIdx.x, lane = tid & 63, wid = tid >> 6;
  int li = lane & 15, gr = lane >> 4;
  int p0 = blockIdx.x*128, m0 = blockIdx.y*64, n = blockIdx.z;
  int pcol = tid & 127, rg = tid >> 7;
  int p = p0 + pcol;
  const u32* wg32 = (const u32*)wg;
  f4 z = {0.f,0.f,0.f,0.f};
  f4 acc[3][2][4];
  #pragma unroll
  for (int g=0;g<3;g++)
    #pragma unroll
    for (int mt=0;mt<2;mt++) { acc[g][mt][0]=z; acc[g][mt][1]=z; acc[g][mt][2]=z; acc[g][mt][3]=z; }
  int wm = (wid & 1)*32, wp = (wid >> 1)*64;
  for (int k0 = 0; k0 < 512; k0 += 32) {
    const u32* src32 = (const u32*)((k0 < 256) ? abf : xin)
        + (size_t)n*128*1296 + (size_t)((k0 & 255)>>1)*1296;
    u32 rx[8];
    #pragma unroll
    for (int j = 0; j < 8; j++) {
      int rp = rg*8 + j;
      rx[j] = (p < 1296) ? src32[(size_t)rp*1296 + p] : 0u;
    }
    *(int4*)&Xs[pcol][SWC(pcol,2*rg)*8]   = *(int4*)&rx[0];
    *(int4*)&Xs[pcol][SWC(pcol,2*rg+1)*8] = *(int4*)&rx[4];
    #pragma unroll
    for (int j = 0; j < 3; j++) {
      int sid = tid + j*256;
      int rid = sid >> 2, q = sid & 3;
      int g = rid >> 6, mm = rid & 63;
      const u32* wsrc = wg32 + (size_t)g*65536 + (size_t)(m0+mm)*256 + (k0>>1) + q*4;
      int4 w4 = *(const int4*)wsrc;
      *(int4*)&Wg[g][mm][SWC(mm,q)*8] = w4;
    }
    __syncthreads();
    bf8 bx[4];
    #pragma unroll
    for (int pt=0;pt<4;pt++) { int r = wp+pt*16+li; bx[pt] = *(bf8*)&Xs[r][SWC(r,gr)*8]; }
    #pragma unroll
    for (int g=0;g<3;g++)
      #pragma unroll
      for (int mt=0;mt<2;mt++) {
        int r = wm+mt*16+li;
        bf8 af = *(bf8*)&Wg[g][r][SWC(r,gr)*8];
        #pragma unroll
        for (int pt=0;pt<4;pt++)
          acc[g][mt][pt] = MFMA(af, bx[pt], acc[g][mt][pt]);
      }
    __syncthreads();
  }
  u32* hn32 = (u32*)hn + (size_t)n*128*1296;
  #pragma unroll
  for (int mt=0;mt<2;mt++)
    #pragma unroll
    for (int pt=0;pt<4;pt++) {
      int rb = m0 + wm + mt*16 + gr*4;
      int pp = p0 + wp + pt*16 + li;
      if (pp < 1296) {
        float hv[4];
        #pragma unroll
        for (int j=0;j<4;j++) {
          float gi = acc[0][mt][pt][j] + b_g[rb+j];
          float gg = acc[1][mt][pt][j] + b_g[512 + rb+j];
          float go = acc[2][mt][pt][j] + b_g[768 + rb+j];
          hv[j] = sigm(go) * tanhf(sigm(gi) * tanhf(gg));
        }
        hn32[(size_t)(rb>>1)*1296 + pp] = cvtpk(hv[0], hv[1]);
        hn32[(size_t)((rb>>1)+1)*1296 + pp] = cvtpk(hv[2], hv[3]);
      }
    }
}

// ---------------- out GEMM: M=256,K=256 over hn (pair-interleaved), out fp32 -------
__global__ __launch_bounds__(256,2) void k_out(const u16* __restrict__ hn,
        const u16* __restrict__ wb, const float* __restrict__ bias,
        float* __restrict__ out) {
  __shared__ alignas(16) u16 Xs[128][40];
  __shared__ alignas(16) u16 Ws[128][40];
  int tid = threadIdx.x, lane = tid & 63, wid = tid >> 6;
  int li = lane & 15, gr = lane >> 4;
  int p0 = blockIdx.x*128, m0 = blockIdx.y*128, n = blockIdx.z;
  int pcol = tid & 127, rg = tid >> 7;
  int wrow = tid >> 1, wh = tid & 1;
  int p = p0 + pcol;
  const u32* src32 = (const u32*)hn + (size_t)n*128*1296;
  const u32* wb32 = (const u32*)wb;
  f4 z = {0.f,0.f,0.f,0.f};
  f4 acc[4][4];
  #pragma unroll
  for (int i=0;i<4;i++) { acc[i][0]=z; acc[i][1]=z; acc[i][2]=z; acc[i][3]=z; }
  int wm = (wid & 1)*64, wp = (wid >> 1)*64;
  for (int k0 = 0; k0 < 256; k0 += 32) {
    u32 rx[8];
    #pragma unroll
    for (int j = 0; j < 8; j++) {
      int rp = rg*8 + j;
      rx[j] = (p < 1296) ? src32[(size_t)((k0>>1) + rp)*1296 + p] : 0u;
    }
    const u32* wsrc = wb32 + (size_t)(m0+wrow)*128 + (k0>>1) + wh*8;
    int4 rwA = *(const int4*)wsrc, rwB = *(const int4*)(wsrc+4);
    *(int4*)&Xs[pcol][SWC(pcol,2*rg)*8]   = *(int4*)&rx[0];
    *(int4*)&Xs[pcol][SWC(pcol,2*rg+1)*8] = *(int4*)&rx[4];
    *(int4*)&Ws[wrow][SWC(wrow,2*wh)*8]   = rwA;
    *(int4*)&Ws[wrow][SWC(wrow,2*wh+1)*8] = rwB;
    __syncthreads();
    bf8 af[4], bx[4];
    #pragma unroll
    for (int mt=0;mt<4;mt++) { int r = wm+mt*16+li; af[mt] = *(bf8*)&Ws[r][SWC(r,gr)*8]; }
    #pragma unroll
    for (int pt=0;pt<4;pt++) { int r = wp+pt*16+li; bx[pt] = *(bf8*)&Xs[r][SWC(r,gr)*8]; }
    #pragma unroll
    for (int mt=0;mt<4;mt++)
      #pragma unroll
      for (int pt=0;pt<4;pt++)
        acc[mt][pt] = MFMA(af[mt], bx[pt], acc[mt][pt]);
    __syncthreads();
  }
  #pragma unroll
  for (int mt=0;mt<4;mt++)
    #pragma unroll
    for (int pt=0;pt<4;pt++)
      #pragma unroll
      for (int j=0;j<4;j++) {
        int m = m0 + wm + mt*16 + gr*4 + j;
        int pp = p0 + wp + pt*16 + li;
        if (pp < 1296) out[((size_t)n*256 + m)*1296 + pp] = acc[mt][pt][j] + bias[m];
      }
}

extern "C" void kernel_launch(void* const* d_in, const int* in_sizes, int n_in,
                              void* d_out, int out_size, void* d_ws, size_t ws_size,
                              hipStream_t stream) {
  const float* x     = (const float*)d_in[0];
  const float* w_in  = (const float*)d_in[1];
  const float* b_in  = (const float*)d_in[2];
  const float* w_qx  = (const float*)d_in[3];
  const float* w_kx  = (const float*)d_in[5];
  const float* w_vx  = (const float*)d_in[7];
  const float* w_ga  = (const float*)d_in[9];
  const float* b_g   = (const float*)d_in[10];
  const float* w_gx  = (const float*)d_in[11];
  const float* w_out = (const float*)d_in[13];
  const float* b_out = (const float*)d_in[14];
  float* out = (float*)d_out;

  u16* ws = (u16*)d_ws;
  size_t o = 0;
  u16* xin_bf = ws + o; o += 2654208;
  u16* qbuf   = ws + o; o += 2654208;
  u16* kbuf   = ws + o; o += 2367488;
  u16* vbuf   = ws + o; o += 2367488;
  u16* abuf   = ws + o; o += 2654208;
  u16* hnb    = ws + o; o += 2654208;
  u16* wqT    = ws + o; o += 589824;
  u16* wkT    = ws + o; o += 589824;
  u16* wvT    = ws + o; o += 589824;
  u16* wgT    = ws + o; o += 393216;
  u16* winb   = ws + o; o += 32768;
  u16* woutb  = ws + o; o += 65536;

  k_prep<<<dim3(2304,5), 256, 0, stream>>>(w_in, w_out, w_qx, w_kx, w_vx,
                                           w_ga, w_gx, winb, woutb, wqT, wkT, wvT, wgT);

  k_xin  <<<dim3(11,2,8), 256, 0, stream>>>(x, winb, b_in, xin_bf);
  k_conv3<<<dim3(16,4,8), 256, 0, stream>>>(xin_bf, wqT, wkT, wvT, qbuf, kbuf, vbuf);
  k_attn <<<dim3(11,8,8), 256, 0, stream>>>(qbuf, kbuf, vbuf, abuf);
  k_gates<<<dim3(11,4,8), 256, 0, stream>>>(abuf, xin_bf, wgT, b_g, hnb);
  k_out  <<<dim3(11,2,8), 256, 0, stream>>>(hnb, woutb, b_out, out);
}

// Round 9
// 200.098 us; speedup vs baseline: 1.8470x; 1.0067x over previous
//
#include <hip/hip_runtime.h>
#include <math.h>

typedef unsigned int u32;
typedef unsigned short u16;
typedef unsigned long long u64;
typedef __attribute__((ext_vector_type(8))) __bf16 bf8;
typedef __attribute__((ext_vector_type(4))) float f4;

#define MFMA(a,b,c) __builtin_amdgcn_mfma_f32_16x16x32_bf16(a,b,c,0,0,0)

// chunk swizzle for 128-row [row][40u16] tiles (xin/gates/out/attn kernels)
#define SWC(row_, c_) ((((((c_)>>1) ^ (((row_)>>3)&1))<<1) | (((c_)&1) ^ (((row_)>>4)&1))))

static __device__ __forceinline__ u32 cvtpk(float lo, float hi) {
  u32 r; asm("v_cvt_pk_bf16_f32 %0, %1, %2" : "=v"(r) : "v"(lo), "v"(hi));
  return r;
}
static __device__ __forceinline__ u16 f2b(float x) { return (u16)cvtpk(x, 0.f); }
static __device__ __forceinline__ float sigm(float x) { return 1.f/(1.f+__expf(-x)); }

// All [256ch][P] bf16 intermediates PAIR-INTERLEAVED: u32 pair q at q*P+p.
// Exception: vbuf plain [256][1156].
// Conv weights FRAGMENT-MAJOR, kg-outer: [72 it = kg*9+tap][16 mb][4 gr][16 li] int4,
// int4 = W[m=mb*16+li][k = (it/9)*32 + gr*8 .. +7] of tap (it%9).

// ---------------- combined weight transforms (1 launch) ----------------
__global__ __launch_bounds__(256) void k_prep(const float* __restrict__ w_in,
        const float* __restrict__ w_out,
        const float* __restrict__ wqx, const float* __restrict__ wkx,
        const float* __restrict__ wvx,
        const float* __restrict__ w_ga, const float* __restrict__ w_gx,
        u16* __restrict__ winb, u16* __restrict__ woutb,
        u16* __restrict__ tq, u16* __restrict__ tk, u16* __restrict__ tv,
        u16* __restrict__ wg) {
  int task = blockIdx.y;
  int i = blockIdx.x*256 + threadIdx.x;
  if (task == 0) {
    if (i < 32768) winb[i] = f2b(w_in[i]);
    else if (i < 98304) woutb[i - 32768] = f2b(w_out[i - 32768]);
  } else if (task <= 3) {
    if (i < 589824) {
      const float* w = (task==1)?wqx:(task==2)?wkx:wvx;
      u16* wt = (task==1)?tq:(task==2)?tk:tv;
      int e = i & 7, li = (i>>3) & 15, gr = (i>>7) & 3, mb = (i>>9) & 15, it = i >> 13;
      int tap = it % 9, kg = it / 9;
      int m = mb*16 + li, k = kg*32 + gr*8 + e;
      wt[i] = f2b(w[(size_t)m*2304 + k*9 + tap]);
    }
  } else {
    if (i < 393216) {
      int g = i >> 17, rem = i & 131071, rr = rem >> 9, kk = rem & 511;
      int gb = (g == 0) ? 0 : (g == 1) ? 512 : 768;
      float v = (kk < 256) ? w_ga[(size_t)(gb+rr)*256 + kk]
                           : w_gx[(size_t)(gb+rr)*256 + kk - 256];
      wg[i] = f2b(v);
    }
  }
}

// ---------------- xin GEMM: M=256,K=128 over x fp32 -> pair-interleaved bf16 ----
__global__ __launch_bounds__(256,2) void k_xin(const float* __restrict__ x,
        const u16* __restrict__ wb, const float* __restrict__ bias,
        u16* __restrict__ out) {
  __shared__ alignas(16) u16 Xs[128][40];
  __shared__ alignas(16) u16 Ws[128][40];
  int tid = threadIdx.x, lane = tid & 63, wid = tid >> 6;
  int li = lane & 15, gr = lane >> 4;
  int p0 = blockIdx.x*128, m0 = blockIdx.y*128, n = blockIdx.z;
  int pcol = tid & 127, rg = tid >> 7;
  int wrow = tid >> 1, wh = tid & 1;
  int p = p0 + pcol;
  const float* src = x + (size_t)n*128*1296;
  const u32* wb32 = (const u32*)wb;
  f4 z = {0.f,0.f,0.f,0.f};
  f4 acc[4][4];
  #pragma unroll
  for (int i=0;i<4;i++) { acc[i][0]=z; acc[i][1]=z; acc[i][2]=z; acc[i][3]=z; }
  int wm = (wid & 1)*64, wp = (wid >> 1)*64;
  for (int k0 = 0; k0 < 128; k0 += 32) {
    u32 rx[8];
    #pragma unroll
    for (int j = 0; j < 8; j++) {
      int rp = rg*8 + j;
      float a = 0.f, b = 0.f;
      if (p < 1296) { a = src[(size_t)(k0+2*rp)*1296+p]; b = src[(size_t)(k0+2*rp+1)*1296+p]; }
      rx[j] = cvtpk(a, b);
    }
    const u32* wsrc = wb32 + (size_t)(m0+wrow)*64 + (k0>>1) + wh*8;
    int4 rwA = *(const int4*)wsrc, rwB = *(const int4*)(wsrc+4);
    *(int4*)&Xs[pcol][SWC(pcol,2*rg)*8]   = *(int4*)&rx[0];
    *(int4*)&Xs[pcol][SWC(pcol,2*rg+1)*8] = *(int4*)&rx[4];
    *(int4*)&Ws[wrow][SWC(wrow,2*wh)*8]   = rwA;
    *(int4*)&Ws[wrow][SWC(wrow,2*wh+1)*8] = rwB;
    __syncthreads();
    bf8 af[4], bx[4];
    #pragma unroll
    for (int mt=0;mt<4;mt++) { int r = wm+mt*16+li; af[mt] = *(bf8*)&Ws[r][SWC(r,gr)*8]; }
    #pragma unroll
    for (int pt=0;pt<4;pt++) { int r = wp+pt*16+li; bx[pt] = *(bf8*)&Xs[r][SWC(r,gr)*8]; }
    #pragma unroll
    for (int mt=0;mt<4;mt++)
      #pragma unroll
      for (int pt=0;pt<4;pt++)
        acc[mt][pt] = MFMA(af[mt], bx[pt], acc[mt][pt]);
    __syncthreads();
  }
  u32* out32 = (u32*)out + (size_t)n*128*1296;
  #pragma unroll
  for (int mt=0;mt<4;mt++)
    #pragma unroll
    for (int pt=0;pt<4;pt++) {
      int mb = m0 + wm + mt*16 + gr*4;
      int pp = p0 + wp + pt*16 + li;
      if (pp < 1296) {
        out32[(size_t)(mb>>1)*1296 + pp] = cvtpk(acc[mt][pt][0]+bias[mb], acc[mt][pt][1]+bias[mb+1]);
        out32[(size_t)((mb>>1)+1)*1296 + pp] = cvtpk(acc[mt][pt][2]+bias[mb+2], acc[mt][pt][3]+bias[mb+3]);
      }
    }
}

// ------- fused q/k/v 3x3 convs: kg-outer HALO-staged X, W in regs -------
// grid (16 tiles: 6 q + 5 k + 5 v, 4 m-quarters, 8 n), 256 threads (4 waves).
// X staged ONCE per 32-ch chunk (halo'd), 9 taps read LDS at precomputed addrs.
__global__ __launch_bounds__(256,2) void k_conv3(const u16* __restrict__ xin,
        const u16* __restrict__ wq, const u16* __restrict__ wk, const u16* __restrict__ wv,
        u16* __restrict__ qb, u16* __restrict__ kb, u16* __restrict__ vb) {
  __shared__ alignas(16) u16 XF[2*384*32];   // 49152 B, two halo planes
  int tid = threadIdx.x, lane = tid & 63, wid = tid >> 6;
  int li = lane & 15, gr = lane >> 4;
  int tile = blockIdx.x, m0 = blockIdx.y*64, n = blockIdx.z;
  int kind, t0;
  if (tile < 6)       { kind = 0; t0 = tile; }
  else if (tile < 11) { kind = 1; t0 = tile - 6; }
  else                { kind = 2; t0 = tile - 11; }
  int P  = kind ? 1156 : 1296;
  int WO = kind ? 34 : 36;
  int px0 = t0*256;
  const u16* wt = (kind==0) ? wq : (kind==1) ? wk : wv;
  const u32* src32 = (const u32*)xin + (size_t)n*128*1296;
  const int4* wt4 = (const int4*)wt;
  int mb0 = m0 >> 4;

  // ---- staging geometry ----
  // q (SAME): 2D halo, rows ry0=px0/36-1 .. +9, cols -1..36 (38 wide), zero-pad.
  // k/v (VALID): linear source range [smin, smin+383], smin = px0 + 2*(px0/34).
  int g0, g1; bool v0, v1;
  if (kind == 0) {
    int ry0 = px0/36 - 1;
    int r_ = tid/38, c_ = tid%38;
    int sy = ry0 + r_, sx = c_ - 1;
    v0 = (sy >= 0 && sy < 36 && sx >= 0 && sx < 36);
    g0 = v0 ? sy*36 + sx : 0;
    int lpx1 = tid + 256;
    r_ = lpx1/38; c_ = lpx1%38;
    sy = ry0 + r_; sx = c_ - 1;
    v1 = (sy >= 0 && sy < 36 && sx >= 0 && sx < 36);
    g1 = v1 ? sy*36 + sx : 0;
  } else {
    int smin = px0 + 2*(px0/34);
    int s0 = smin + tid, s1 = smin + tid + 256;
    v0 = s0 < 1296; v1 = s1 < 1296;
    g0 = v0 ? s0 : 0; g1 = v1 ? s1 : 0;
  }
  int sw0 = (tid >> 1) & 3;

  // ---- per-lane read addresses rdo[pt][tap] (u16 index in a plane) ----
  int rdo[4][9];
  {
    int rs = kind ? 36 : 38;
    int py0q = px0/36, smin = px0 + 2*(px0/34);
    #pragma unroll
    for (int pt = 0; pt < 4; pt++) {
      int p = px0 + wid*64 + pt*16 + li;
      if (p > P-1) p = P-1;
      int py = p / WO, pxc = p % WO;
      int lb = kind ? (p + 2*py - smin) : ((py - py0q)*38 + pxc);
      #pragma unroll
      for (int tp = 0; tp < 9; tp++) {
        int lp = lb + (tp/3)*rs + tp%3;
        rdo[pt][tp] = lp*32 + ((gr ^ ((lp>>1)&3)) << 3);
      }
    }
  }

  f4 z = {0.f,0.f,0.f,0.f};
  f4 acc[4][4];
  #pragma unroll
  for (int i=0;i<4;i++) { acc[i][0]=z; acc[i][1]=z; acc[i][2]=z; acc[i][3]=z; }
  u32 sA[16], sB[16];
  int4 wbuf[2][4];

  #define STAGELOAD(kg_) { \
    const u32* s_ = src32 + (size_t)((kg_)*16)*1296; \
    _Pragma("unroll") \
    for (int j = 0; j < 16; j++) sA[j] = v0 ? s_[(size_t)j*1296 + g0] : 0u; \
    if (tid < 128) { \
      _Pragma("unroll") \
      for (int j = 0; j < 16; j++) sB[j] = v1 ? s_[(size_t)j*1296 + g1] : 0u; \
    } }

  #define WRITESTAGE(bb_) { \
    u16* pl_ = &XF[(bb_)*12288]; \
    _Pragma("unroll") \
    for (int c = 0; c < 4; c++) \
      *(int4*)&pl_[tid*32 + ((c ^ sw0) << 3)] = *(int4*)&sA[c*4]; \
    if (tid < 128) { \
      _Pragma("unroll") \
      for (int c = 0; c < 4; c++) \
        *(int4*)&pl_[(tid+256)*32 + ((c ^ sw0) << 3)] = *(int4*)&sB[c*4]; \
    } }

  #define LOADW(it_) { \
    const int4* ws_ = wt4 + ((size_t)(it_)*16 + mb0)*64 + lane; \
    _Pragma("unroll") \
    for (int mt = 0; mt < 4; mt++) wbuf[(it_)&1][mt] = ws_[(size_t)mt*64]; }

  #define TAP(kg_, tap_) { \
    if ((kg_)*9 + (tap_) < 71) LOADW((kg_)*9 + (tap_) + 1); \
    const u16* pl_ = &XF[((kg_)&1)*12288]; \
    bf8 bx_[4]; \
    _Pragma("unroll") \
    for (int pt = 0; pt < 4; pt++) bx_[pt] = *(bf8*)&pl_[rdo[pt][tap_]]; \
    _Pragma("unroll") \
    for (int mt = 0; mt < 4; mt++) \
      _Pragma("unroll") \
      for (int pt = 0; pt < 4; pt++) \
        acc[mt][pt] = MFMA(*(bf8*)&wbuf[((kg_)*9+(tap_))&1][mt], bx_[pt], acc[mt][pt]); }

  #define KGBODY(kg_) { \
    if ((kg_) < 7) STAGELOAD((kg_)+1); \
    TAP(kg_,0) TAP(kg_,1) TAP(kg_,2) TAP(kg_,3) TAP(kg_,4) \
    TAP(kg_,5) TAP(kg_,6) TAP(kg_,7) TAP(kg_,8) \
    if ((kg_) < 7) { WRITESTAGE(((kg_)+1)&1); __syncthreads(); } }

  STAGELOAD(0);
  LOADW(0);
  WRITESTAGE(0);
  __syncthreads();
  KGBODY(0) KGBODY(1) KGBODY(2) KGBODY(3)
  KGBODY(4) KGBODY(5) KGBODY(6) KGBODY(7)
  #undef STAGELOAD
  #undef WRITESTAGE
  #undef LOADW
  #undef TAP
  #undef KGBODY

  if (kind <= 1) {
    u32* dst32 = (u32*)(kind==0 ? qb : kb) + (size_t)n*128*P;
    #pragma unroll
    for (int mt=0;mt<4;mt++)
      #pragma unroll
      for (int pt=0;pt<4;pt++) {
        int mb = m0 + mt*16 + gr*4;
        int pp = px0 + wid*64 + pt*16 + li;
        if (pp < P) {
          dst32[(size_t)(mb>>1)*P + pp] = cvtpk(acc[mt][pt][0], acc[mt][pt][1]);
          dst32[(size_t)((mb>>1)+1)*P + pp] = cvtpk(acc[mt][pt][2], acc[mt][pt][3]);
        }
      }
  } else {
    #pragma unroll
    for (int mt=0;mt<4;mt++)
      #pragma unroll
      for (int pt=0;pt<4;pt++) {
        int pp = px0 + wid*64 + pt*16 + li;
        if (pp < P) {
          #pragma unroll
          for (int j=0;j<4;j++) {
            int m = m0 + mt*16 + gr*4 + j;
            vb[((size_t)n*256 + m)*1156 + pp] = f2b(acc[mt][pt][j]);
          }
        }
      }
  }
}

// ---------------- flash attention, MFMA, online softmax (defer-max) ----------------
__global__ __launch_bounds__(256,2) void k_attn(const u16* __restrict__ qbf,
        const u16* __restrict__ kbf, const u16* __restrict__ vbf, u16* __restrict__ abf) {
  __shared__ alignas(16) u16 Qs[128][40];
  __shared__ alignas(16) u16 Ks[64][40];
  __shared__ alignas(16) u16 Vs[2][32][40];
  __shared__ alignas(16) u16 Ps[4][2][32][40];
  int tid = threadIdx.x, lane = tid & 63, wid = tid >> 6;
  int li = lane & 15, gr = lane >> 4;
  int h = blockIdx.y, n = blockIdx.z;
  int q0 = blockIdx.x*128;
  const u32* Qp32 = (const u32*)qbf + ((size_t)n*128 + h*16)*1296;
  const u32* Kp32 = (const u32*)kbf + ((size_t)n*128 + h*16)*1156;
  const u16* Vp = vbf + ((size_t)n*256 + h*32)*1156;
  #pragma unroll
  for (int j = 0; j < 8; j++) {
    int idx = tid + j*256, qq = idx >> 4, cp = idx & 15;
    int gq = q0 + qq;
    ((u32*)&Qs[qq][0])[cp] = (gq < 1296) ? Qp32[(size_t)cp*1296 + gq] : 0u;
  }
  f4 z = {0.f,0.f,0.f,0.f};
  float mx[2] = {-1e30f, -1e30f}, ls[2] = {0.f, 0.f};
  f4 accO[2][2] = {{z,z},{z,z}};
  int wq = wid*32;
  int kdd = tid >> 2, kq = tid & 3;
  __syncthreads();
  for (int d0 = 0; d0 < 1156; d0 += 64) {
    {
      u32 kk[4];
      int gd = d0 + kdd;
      #pragma unroll
      for (int i = 0; i < 4; i++)
        kk[i] = (gd < 1156) ? Kp32[(size_t)(kq*4+i)*1156 + gd] : 0u;
      *(int4*)&Ks[kdd][SWC(kdd,kq)*8] = *(int4*)&kk[0];
    }
    #pragma unroll
    for (int j = 0; j < 4; j++) {
      int idx = tid + j*256, half = idx >> 9, rem = idx & 511;
      int cc = rem >> 4, dp = rem & 15;
      int gd = d0 + half*32 + dp*2; u32 v = 0;
      if (gd < 1156) v = *(const u32*)&Vp[(size_t)cc*1156 + gd];
      ((u32*)&Vs[half][cc][0])[dp] = v;
    }
    __syncthreads();
    bf8 ak[4], bq[2];
    #pragma unroll
    for (int dt=0;dt<4;dt++) { int r = dt*16+li; ak[dt] = *(bf8*)&Ks[r][SWC(r,gr)*8]; }
    #pragma unroll
    for (int qt=0;qt<2;qt++) bq[qt] = *(bf8*)&Qs[wq + qt*16 + li][8*gr];
    f4 s[2][4];
    #pragma unroll
    for (int qt=0;qt<2;qt++)
      #pragma unroll
      for (int dt=0;dt<4;dt++)
        s[qt][dt] = MFMA(ak[dt], bq[qt], z);
    bool tail = (d0 + 64 > 1156);
    #pragma unroll
    for (int qt=0;qt<2;qt++) {
      if (tail) {
        #pragma unroll
        for (int dt=0;dt<4;dt++)
          #pragma unroll
          for (int j=0;j<4;j++)
            if (d0 + dt*16 + gr*4 + j >= 1156) s[qt][dt][j] = -1e30f;
      }
      float tm = -1e30f;
      #pragma unroll
      for (int dt=0;dt<4;dt++)
        #pragma unroll
        for (int j=0;j<4;j++) tm = fmaxf(tm, s[qt][dt][j]);
      tm = fmaxf(tm, __shfl_xor(tm, 16));
      tm = fmaxf(tm, __shfl_xor(tm, 32));
      if (__any(tm > mx[qt] + 8.f)) {
        float nm = fmaxf(mx[qt], tm);
        float corr = __expf(mx[qt] - nm);
        mx[qt] = nm;
        ls[qt] *= corr;
        accO[0][qt] *= corr; accO[1][qt] *= corr;
      }
      float rs = 0.f;
      #pragma unroll
      for (int dt=0;dt<4;dt++)
        #pragma unroll
        for (int j=0;j<4;j++) {
          float e = __expf(s[qt][dt][j] - mx[qt]);
          s[qt][dt][j] = e; rs += e;
        }
      rs += __shfl_xor(rs, 16); rs += __shfl_xor(rs, 32);
      ls[qt] += rs;
      #pragma unroll
      for (int dt=0;dt<4;dt++) {
        u32 lo_ = cvtpk(s[qt][dt][0], s[qt][dt][1]);
        u32 hi_ = cvtpk(s[qt][dt][2], s[qt][dt][3]);
        u64 pk = (u64)lo_ | ((u64)hi_ << 32);
        *(u64*)&Ps[wid][dt>>1][qt*16 + li][(dt&1)*16 + gr*4] = pk;
      }
    }
    #pragma unroll
    for (int kt=0;kt<2;kt++) {
      bf8 av0 = *(bf8*)&Vs[kt][li][8*gr];
      bf8 av1 = *(bf8*)&Vs[kt][16 + li][8*gr];
      bf8 bp0 = *(bf8*)&Ps[wid][kt][li][8*gr];
      bf8 bp1 = *(bf8*)&Ps[wid][kt][16 + li][8*gr];
      accO[0][0] = MFMA(av0, bp0, accO[0][0]);
      accO[0][1] = MFMA(av0, bp1, accO[0][1]);
      accO[1][0] = MFMA(av1, bp0, accO[1][0]);
      accO[1][1] = MFMA(av1, bp1, accO[1][1]);
    }
    __syncthreads();
  }
  u32* ab32 = (u32*)abf + (size_t)n*128*1296;
  #pragma unroll
  for (int qt=0;qt<2;qt++) {
    float inv = 1.f / ls[qt];
    #pragma unroll
    for (int mt=0;mt<2;mt++) {
      int cb = h*32 + mt*16 + gr*4;
      int gq = q0 + wq + qt*16 + li;
      if (gq < 1296) {
        ab32[(size_t)(cb>>1)*1296 + gq] = cvtpk(accO[mt][qt][0]*inv, accO[mt][qt][1]*inv);
        ab32[(size_t)((cb>>1)+1)*1296 + gq] = cvtpk(accO[mt][qt][2]*inv, accO[mt][qt][3]*inv);
      }
    }
  }
}

// ---------------- fused gates GEMM (i,g,o; K=512) + LSTM nonlinearity ----------------
__global__ __launch_bounds__(256,2) void k_gates(const u16* __restrict__ abf,
        const u16* __restrict__ xin, const u16* __restrict__ wg,
        const float* __restrict__ b_g, u16* __restrict__ hn) {
  __shared__ alignas(16) u16 Xs[128][40];
  __shared__ alignas(16) u16 Wg[3][64][40];
  int tid = threadIdx.x, lane = tid & 63, wid = tid >> 6;
  int li = lane & 15, gr = lane >> 4;
  int p0 = blockIdx.x*128, m0 = blockIdx.y*64, n = blockIdx.z;
  int pcol = tid & 127, rg = tid >> 7;
  int p = p0 + pcol;
  const u32* wg32 = (const u32*)wg;
  f4 z = {0.f,0.f,0.f,0.f};
  f4 acc[3][2][4];
  #pragma unroll
  for (int g=0;g<3;g++)
    #pragma unroll
    for (int mt=0;mt<2;mt++) { acc[g][mt][0]=z; acc[g][mt][1]=z; acc[g][mt][2]=z; acc[g][mt][3]=z; }
  int wm = (wid & 1)*32, wp = (wid >> 1)*64;
  for (int k0 = 0; k0 < 512; k0 += 32) {
    const u32* src32 = (const u32*)((k0 < 256) ? abf : xin)
        + (size_t)n*128*1296 + (size_t)((k0 & 255)>>1)*1296;
    u32 rx[8];
    #pragma unroll
    for (int j = 0; j < 8; j++) {
      int rp = rg*8 + j;
      rx[j] = (p < 1296) ? src32[(size_t)rp*1296 + p] : 0u;
    }
    *(int4*)&Xs[pcol][SWC(pcol,2*rg)*8]   = *(int4*)&rx[0];
    *(int4*)&Xs[pcol][SWC(pcol,2*rg+1)*8] = *(int4*)&rx[4];
    #pragma unroll
    for (int j = 0; j < 3; j++) {
      int sid = tid + j*256;
      int rid = sid >> 2, q = sid & 3;
      int g = rid >> 6, mm = rid & 63;
      const u32* wsrc = wg32 + (size_t)g*65536 + (size_t)(m0+mm)*256 + (k0>>1) + q*4;
      int4 w4 = *(const int4*)wsrc;
      *(int4*)&Wg[g][mm][SWC(mm,q)*8] = w4;
    }
    __syncthreads();
    bf8 bx[4];
    #pragma unroll
    for (int pt=0;pt<4;pt++) { int r = wp+pt*16+li; bx[pt] = *(bf8*)&Xs[r][SWC(r,gr)*8]; }
    #pragma unroll
    for (int g=0;g<3;g++)
      #pragma unroll
      for (int mt=0;mt<2;mt++) {
        int r = wm+mt*16+li;
        bf8 af = *(bf8*)&Wg[g][r][SWC(r,gr)*8];
        #pragma unroll
        for (int pt=0;pt<4;pt++)
          acc[g][mt][pt] = MFMA(af, bx[pt], acc[g][mt][pt]);
      }
    __syncthreads();
  }
  u32* hn32 = (u32*)hn + (size_t)n*128*1296;
  #pragma unroll
  for (int mt=0;mt<2;mt++)
    #pragma unroll
    for (int pt=0;pt<4;pt++) {
      int rb = m0 + wm + mt*16 + gr*4;
      int pp = p0 + wp + pt*16 + li;
      if (pp < 1296) {
        float hv[4];
        #pragma unroll
        for (int j=0;j<4;j++) {
          float gi = acc[0][mt][pt][j] + b_g[rb+j];
          float gg = acc[1][mt][pt][j] + b_g[512 + rb+j];
          float go = acc[2][mt][pt][j] + b_g[768 + rb+j];
          hv[j] = sigm(go) * tanhf(sigm(gi) * tanhf(gg));
        }
        hn32[(size_t)(rb>>1)*1296 + pp] = cvtpk(hv[0], hv[1]);
        hn32[(size_t)((rb>>1)+1)*1296 + pp] = cvtpk(hv[2], hv[3]);
      }
    }
}

// ---------------- out GEMM: M=256,K=256 over hn (pair-interleaved), out fp32 -------
__global__ __launch_bounds__(256,2) void k_out(const u16* __restrict__ hn,
        const u16* __restrict__ wb, const float* __restrict__ bias,
        float* __restrict__ out) {
  __shared__ alignas(16) u16 Xs[128][40];
  __shared__ alignas(16) u16 Ws[128][40];
  int tid = threadIdx.x, lane = tid & 63, wid = tid >> 6;
  int li = lane & 15, gr = lane >> 4;
  int p0 = blockIdx.x*128, m0 = blockIdx.y*128, n = blockIdx.z;
  int pcol = tid & 127, rg = tid >> 7;
  int wrow = tid >> 1, wh = tid & 1;
  int p = p0 + pcol;
  const u32* src32 = (const u32*)hn + (size_t)n*128*1296;
  const u32* wb32 = (const u32*)wb;
  f4 z = {0.f,0.f,0.f,0.f};
  f4 acc[4][4];
  #pragma unroll
  for (int i=0;i<4;i++) { acc[i][0]=z; acc[i][1]=z; acc[i][2]=z; acc[i][3]=z; }
  int wm = (wid & 1)*64, wp = (wid >> 1)*64;
  for (int k0 = 0; k0 < 256; k0 += 32) {
    u32 rx[8];
    #pragma unroll
    for (int j = 0; j < 8; j++) {
      int rp = rg*8 + j;
      rx[j] = (p < 1296) ? src32[(size_t)((k0>>1) + rp)*1296 + p] : 0u;
    }
    const u32* wsrc = wb32 + (size_t)(m0+wrow)*128 + (k0>>1) + wh*8;
    int4 rwA = *(const int4*)wsrc, rwB = *(const int4*)(wsrc+4);
    *(int4*)&Xs[pcol][SWC(pcol,2*rg)*8]   = *(int4*)&rx[0];
    *(int4*)&Xs[pcol][SWC(pcol,2*rg+1)*8] = *(int4*)&rx[4];
    *(int4*)&Ws[wrow][SWC(wrow,2*wh)*8]   = rwA;
    *(int4*)&Ws[wrow][SWC(wrow,2*wh+1)*8] = rwB;
    __syncthreads();
    bf8 af[4], bx[4];
    #pragma unroll
    for (int mt=0;mt<4;mt++) { int r = wm+mt*16+li; af[mt] = *(bf8*)&Ws[r][SWC(r,gr)*8]; }
    #pragma unroll
    for (int pt=0;pt<4;pt++) { int r = wp+pt*16+li; bx[pt] = *(bf8*)&Xs[r][SWC(r,gr)*8]; }
    #pragma unroll
    for (int mt=0;mt<4;mt++)
      #pragma unroll
      for (int pt=0;pt<4;pt++)
        acc[mt][pt] = MFMA(af[mt], bx[pt], acc[mt][pt]);
    __syncthreads();
  }
  #pragma unroll
  for (int mt=0;mt<4;mt++)
    #pragma unroll
    for (int pt=0;pt<4;pt++)
      #pragma unroll
      for (int j=0;j<4;j++) {
        int m = m0 + wm + mt*16 + gr*4 + j;
        int pp = p0 + wp + pt*16 + li;
        if (pp < 1296) out[((size_t)n*256 + m)*1296 + pp] = acc[mt][pt][j] + bias[m];
      }
}

extern "C" void kernel_launch(void* const* d_in, const int* in_sizes, int n_in,
                              void* d_out, int out_size, void* d_ws, size_t ws_size,
                              hipStream_t stream) {
  const float* x     = (const float*)d_in[0];
  const float* w_in  = (const float*)d_in[1];
  const float* b_in  = (const float*)d_in[2];
  const float* w_qx  = (const float*)d_in[3];
  const float* w_kx  = (const float*)d_in[5];
  const float* w_vx  = (const float*)d_in[7];
  const float* w_ga  = (const float*)d_in[9];
  const float* b_g   = (const float*)d_in[10];
  const float* w_gx  = (const float*)d_in[11];
  const float* w_out = (const float*)d_in[13];
  const float* b_out = (const float*)d_in[14];
  float* out = (float*)d_out;

  u16* ws = (u16*)d_ws;
  size_t o = 0;
  u16* xin_bf = ws + o; o += 2654208;
  u16* qbuf   = ws + o; o += 2654208;
  u16* kbuf   = ws + o; o += 2367488;
  u16* vbuf   = ws + o; o += 2367488;
  u16* abuf   = ws + o; o += 2654208;
  u16* hnb    = ws + o; o += 2654208;
  u16* wqT    = ws + o; o += 589824;
  u16* wkT    = ws + o; o += 589824;
  u16* wvT    = ws + o; o += 589824;
  u16* wgT    = ws + o; o += 393216;
  u16* winb   = ws + o; o += 32768;
  u16* woutb  = ws + o; o += 65536;

  k_prep<<<dim3(2304,5), 256, 0, stream>>>(w_in, w_out, w_qx, w_kx, w_vx,
                                           w_ga, w_gx, winb, woutb, wqT, wkT, wvT, wgT);

  k_xin  <<<dim3(11,2,8), 256, 0, stream>>>(x, winb, b_in, xin_bf);
  k_conv3<<<dim3(16,4,8), 256, 0, stream>>>(xin_bf, wqT, wkT, wvT, qbuf, kbuf, vbuf);
  k_attn <<<dim3(11,8,8), 256, 0, stream>>>(qbuf, kbuf, vbuf, abuf);
  k_gates<<<dim3(11,4,8), 256, 0, stream>>>(abuf, xin_bf, wgT, b_g, hnb);
  k_out  <<<dim3(11,2,8), 256, 0, stream>>>(hnb, woutb, b_out, out);
}

// Round 10
// 195.165 us; speedup vs baseline: 1.8936x; 1.0253x over previous
//
#include <hip/hip_runtime.h>
#include <math.h>

typedef unsigned int u32;
typedef unsigned short u16;
typedef unsigned long long u64;
typedef __attribute__((ext_vector_type(8))) __bf16 bf8;
typedef __attribute__((ext_vector_type(4))) float f4;

#define MFMA(a,b,c) __builtin_amdgcn_mfma_f32_16x16x32_bf16(a,b,c,0,0,0)

// chunk swizzle for 128-row [row][40u16] tiles (xin/gates/out/attn kernels)
#define SWC(row_, c_) ((((((c_)>>1) ^ (((row_)>>3)&1))<<1) | (((c_)&1) ^ (((row_)>>4)&1))))

static __device__ __forceinline__ u32 cvtpk(float lo, float hi) {
  u32 r; asm("v_cvt_pk_bf16_f32 %0, %1, %2" : "=v"(r) : "v"(lo), "v"(hi));
  return r;
}
static __device__ __forceinline__ u16 f2b(float x) { return (u16)cvtpk(x, 0.f); }
static __device__ __forceinline__ float sigm(float x) { return 1.f/(1.f+__expf(-x)); }

// All [256ch][P] bf16 intermediates PAIR-INTERLEAVED: u32 pair q at q*P+p.
// Exception: vbuf plain [256][1156].
// Conv weights FRAGMENT-MAJOR, kg-outer: [72 it = kg*9+tap][16 mb][4 gr][16 li] int4,
// int4 = W[m=mb*16+li][k = (it/9)*32 + gr*8 .. +7] of tap (it%9).

// ---------------- combined weight transforms (1 launch) ----------------
__global__ __launch_bounds__(256) void k_prep(const float* __restrict__ w_in,
        const float* __restrict__ w_out,
        const float* __restrict__ wqx, const float* __restrict__ wkx,
        const float* __restrict__ wvx,
        const float* __restrict__ w_ga, const float* __restrict__ w_gx,
        u16* __restrict__ winb, u16* __restrict__ woutb,
        u16* __restrict__ tq, u16* __restrict__ tk, u16* __restrict__ tv,
        u16* __restrict__ wg) {
  int task = blockIdx.y;
  int i = blockIdx.x*256 + threadIdx.x;
  if (task == 0) {
    if (i < 32768) winb[i] = f2b(w_in[i]);
    else if (i < 98304) woutb[i - 32768] = f2b(w_out[i - 32768]);
  } else if (task <= 3) {
    if (i < 589824) {
      const float* w = (task==1)?wqx:(task==2)?wkx:wvx;
      u16* wt = (task==1)?tq:(task==2)?tk:tv;
      int e = i & 7, li = (i>>3) & 15, gr = (i>>7) & 3, mb = (i>>9) & 15, it = i >> 13;
      int tap = it % 9, kg = it / 9;
      int m = mb*16 + li, k = kg*32 + gr*8 + e;
      wt[i] = f2b(w[(size_t)m*2304 + k*9 + tap]);
    }
  } else {
    if (i < 393216) {
      int g = i >> 17, rem = i & 131071, rr = rem >> 9, kk = rem & 511;
      int gb = (g == 0) ? 0 : (g == 1) ? 512 : 768;
      float v = (kk < 256) ? w_ga[(size_t)(gb+rr)*256 + kk]
                           : w_gx[(size_t)(gb+rr)*256 + kk - 256];
      wg[i] = f2b(v);
    }
  }
}

// ---------------- xin GEMM: M=256,K=128 over x fp32 -> pair-interleaved bf16 ----
__global__ __launch_bounds__(256,2) void k_xin(const float* __restrict__ x,
        const u16* __restrict__ wb, const float* __restrict__ bias,
        u16* __restrict__ out) {
  __shared__ alignas(16) u16 Xs[128][40];
  __shared__ alignas(16) u16 Ws[128][40];
  int tid = threadIdx.x, lane = tid & 63, wid = tid >> 6;
  int li = lane & 15, gr = lane >> 4;
  int p0 = blockIdx.x*128, m0 = blockIdx.y*128, n = blockIdx.z;
  int pcol = tid & 127, rg = tid >> 7;
  int wrow = tid >> 1, wh = tid & 1;
  int p = p0 + pcol;
  const float* src = x + (size_t)n*128*1296;
  const u32* wb32 = (const u32*)wb;
  f4 z = {0.f,0.f,0.f,0.f};
  f4 acc[4][4];
  #pragma unroll
  for (int i=0;i<4;i++) { acc[i][0]=z; acc[i][1]=z; acc[i][2]=z; acc[i][3]=z; }
  int wm = (wid & 1)*64, wp = (wid >> 1)*64;
  for (int k0 = 0; k0 < 128; k0 += 32) {
    u32 rx[8];
    #pragma unroll
    for (int j = 0; j < 8; j++) {
      int rp = rg*8 + j;
      float a = 0.f, b = 0.f;
      if (p < 1296) { a = src[(size_t)(k0+2*rp)*1296+p]; b = src[(size_t)(k0+2*rp+1)*1296+p]; }
      rx[j] = cvtpk(a, b);
    }
    const u32* wsrc = wb32 + (size_t)(m0+wrow)*64 + (k0>>1) + wh*8;
    int4 rwA = *(const int4*)wsrc, rwB = *(const int4*)(wsrc+4);
    *(int4*)&Xs[pcol][SWC(pcol,2*rg)*8]   = *(int4*)&rx[0];
    *(int4*)&Xs[pcol][SWC(pcol,2*rg+1)*8] = *(int4*)&rx[4];
    *(int4*)&Ws[wrow][SWC(wrow,2*wh)*8]   = rwA;
    *(int4*)&Ws[wrow][SWC(wrow,2*wh+1)*8] = rwB;
    __syncthreads();
    bf8 af[4], bx[4];
    #pragma unroll
    for (int mt=0;mt<4;mt++) { int r = wm+mt*16+li; af[mt] = *(bf8*)&Ws[r][SWC(r,gr)*8]; }
    #pragma unroll
    for (int pt=0;pt<4;pt++) { int r = wp+pt*16+li; bx[pt] = *(bf8*)&Xs[r][SWC(r,gr)*8]; }
    #pragma unroll
    for (int mt=0;mt<4;mt++)
      #pragma unroll
      for (int pt=0;pt<4;pt++)
        acc[mt][pt] = MFMA(af[mt], bx[pt], acc[mt][pt]);
    __syncthreads();
  }
  u32* out32 = (u32*)out + (size_t)n*128*1296;
  #pragma unroll
  for (int mt=0;mt<4;mt++)
    #pragma unroll
    for (int pt=0;pt<4;pt++) {
      int mb = m0 + wm + mt*16 + gr*4;
      int pp = p0 + wp + pt*16 + li;
      if (pp < 1296) {
        out32[(size_t)(mb>>1)*1296 + pp] = cvtpk(acc[mt][pt][0]+bias[mb], acc[mt][pt][1]+bias[mb+1]);
        out32[(size_t)((mb>>1)+1)*1296 + pp] = cvtpk(acc[mt][pt][2]+bias[mb+2], acc[mt][pt][3]+bias[mb+3]);
      }
    }
}

// ------- fused q/k/v 3x3 convs: kg-outer HALO-staged X, W ring depth 4 -------
// grid (16 tiles: 6 q + 5 k + 5 v, 4 m-quarters, 8 n), 256 threads (4 waves).
// X staged ONCE per 32-ch chunk (halo'd); 9 taps read LDS at precomputed addrs.
// W prefetched 3 taps ahead (ring of 4) so load->use distance ~ L2 latency.
__global__ __launch_bounds__(256,2) void k_conv3(const u16* __restrict__ xin,
        const u16* __restrict__ wq, const u16* __restrict__ wk, const u16* __restrict__ wv,
        u16* __restrict__ qb, u16* __restrict__ kb, u16* __restrict__ vb) {
  __shared__ alignas(16) u16 XF[2*384*32];   // 49152 B, two halo planes
  int tid = threadIdx.x, lane = tid & 63, wid = tid >> 6;
  int li = lane & 15, gr = lane >> 4;
  int tile = blockIdx.x, m0 = blockIdx.y*64, n = blockIdx.z;
  int kind, t0;
  if (tile < 6)       { kind = 0; t0 = tile; }
  else if (tile < 11) { kind = 1; t0 = tile - 6; }
  else                { kind = 2; t0 = tile - 11; }
  int P  = kind ? 1156 : 1296;
  int WO = kind ? 34 : 36;
  int px0 = t0*256;
  const u16* wt = (kind==0) ? wq : (kind==1) ? wk : wv;
  const u32* src32 = (const u32*)xin + (size_t)n*128*1296;
  const int4* wt4 = (const int4*)wt;
  int mb0 = m0 >> 4;

  // ---- staging geometry ----
  int g0, g1; bool v0, v1;
  if (kind == 0) {
    int ry0 = px0/36 - 1;
    int r_ = tid/38, c_ = tid%38;
    int sy = ry0 + r_, sx = c_ - 1;
    v0 = (sy >= 0 && sy < 36 && sx >= 0 && sx < 36);
    g0 = v0 ? sy*36 + sx : 0;
    int lpx1 = tid + 256;
    r_ = lpx1/38; c_ = lpx1%38;
    sy = ry0 + r_; sx = c_ - 1;
    v1 = (sy >= 0 && sy < 36 && sx >= 0 && sx < 36);
    g1 = v1 ? sy*36 + sx : 0;
  } else {
    int smin = px0 + 2*(px0/34);
    int s0 = smin + tid, s1 = smin + tid + 256;
    v0 = s0 < 1296; v1 = s1 < 1296;
    g0 = v0 ? s0 : 0; g1 = v1 ? s1 : 0;
  }
  int sw0 = (tid >> 1) & 3;

  // ---- per-lane read addresses rdo[pt][tap] ----
  int rdo[4][9];
  {
    int rs = kind ? 36 : 38;
    int py0q = px0/36, smin = px0 + 2*(px0/34);
    #pragma unroll
    for (int pt = 0; pt < 4; pt++) {
      int p = px0 + wid*64 + pt*16 + li;
      if (p > P-1) p = P-1;
      int py = p / WO, pxc = p % WO;
      int lb = kind ? (p + 2*py - smin) : ((py - py0q)*38 + pxc);
      #pragma unroll
      for (int tp = 0; tp < 9; tp++) {
        int lp = lb + (tp/3)*rs + tp%3;
        rdo[pt][tp] = lp*32 + ((gr ^ ((lp>>1)&3)) << 3);
      }
    }
  }

  f4 z = {0.f,0.f,0.f,0.f};
  f4 acc[4][4];
  #pragma unroll
  for (int i=0;i<4;i++) { acc[i][0]=z; acc[i][1]=z; acc[i][2]=z; acc[i][3]=z; }
  u32 sA[16], sB[16];
  int4 wbuf[4][4];

  #define STAGELOAD(kg_) { \
    const u32* s_ = src32 + (size_t)((kg_)*16)*1296; \
    _Pragma("unroll") \
    for (int j = 0; j < 16; j++) sA[j] = v0 ? s_[(size_t)j*1296 + g0] : 0u; \
    if (tid < 128) { \
      _Pragma("unroll") \
      for (int j = 0; j < 16; j++) sB[j] = v1 ? s_[(size_t)j*1296 + g1] : 0u; \
    } }

  #define WRITESTAGE(bb_) { \
    u16* pl_ = &XF[(bb_)*12288]; \
    _Pragma("unroll") \
    for (int c = 0; c < 4; c++) \
      *(int4*)&pl_[tid*32 + ((c ^ sw0) << 3)] = *(int4*)&sA[c*4]; \
    if (tid < 128) { \
      _Pragma("unroll") \
      for (int c = 0; c < 4; c++) \
        *(int4*)&pl_[(tid+256)*32 + ((c ^ sw0) << 3)] = *(int4*)&sB[c*4]; \
    } }

  #define LOADW(it_) { \
    const int4* ws_ = wt4 + ((size_t)(it_)*16 + mb0)*64 + lane; \
    _Pragma("unroll") \
    for (int mt = 0; mt < 4; mt++) wbuf[(it_)&3][mt] = ws_[(size_t)mt*64]; }

  #define TAP(kg_, tap_) { \
    if ((kg_)*9 + (tap_) < 69) LOADW((kg_)*9 + (tap_) + 3); \
    const u16* pl_ = &XF[((kg_)&1)*12288]; \
    bf8 bx_[4]; \
    _Pragma("unroll") \
    for (int pt = 0; pt < 4; pt++) bx_[pt] = *(bf8*)&pl_[rdo[pt][tap_]]; \
    _Pragma("unroll") \
    for (int mt = 0; mt < 4; mt++) \
      _Pragma("unroll") \
      for (int pt = 0; pt < 4; pt++) \
        acc[mt][pt] = MFMA(*(bf8*)&wbuf[((kg_)*9+(tap_))&3][mt], bx_[pt], acc[mt][pt]); }

  #define KGBODY(kg_) { \
    if ((kg_) < 7) STAGELOAD((kg_)+1); \
    TAP(kg_,0) TAP(kg_,1) TAP(kg_,2) TAP(kg_,3) TAP(kg_,4) \
    TAP(kg_,5) TAP(kg_,6) TAP(kg_,7) TAP(kg_,8) \
    if ((kg_) < 7) { WRITESTAGE(((kg_)+1)&1); __syncthreads(); } }

  STAGELOAD(0);
  LOADW(0); LOADW(1); LOADW(2);
  WRITESTAGE(0);
  __syncthreads();
  KGBODY(0) KGBODY(1) KGBODY(2) KGBODY(3)
  KGBODY(4) KGBODY(5) KGBODY(6) KGBODY(7)
  #undef STAGELOAD
  #undef WRITESTAGE
  #undef LOADW
  #undef TAP
  #undef KGBODY

  if (kind <= 1) {
    u32* dst32 = (u32*)(kind==0 ? qb : kb) + (size_t)n*128*P;
    #pragma unroll
    for (int mt=0;mt<4;mt++)
      #pragma unroll
      for (int pt=0;pt<4;pt++) {
        int mb = m0 + mt*16 + gr*4;
        int pp = px0 + wid*64 + pt*16 + li;
        if (pp < P) {
          dst32[(size_t)(mb>>1)*P + pp] = cvtpk(acc[mt][pt][0], acc[mt][pt][1]);
          dst32[(size_t)((mb>>1)+1)*P + pp] = cvtpk(acc[mt][pt][2], acc[mt][pt][3]);
        }
      }
  } else {
    #pragma unroll
    for (int mt=0;mt<4;mt++)
      #pragma unroll
      for (int pt=0;pt<4;pt++) {
        int pp = px0 + wid*64 + pt*16 + li;
        if (pp < P) {
          #pragma unroll
          for (int j=0;j<4;j++) {
            int m = m0 + mt*16 + gr*4 + j;
            vb[((size_t)n*256 + m)*1156 + pp] = f2b(acc[mt][pt][j]);
          }
        }
      }
  }
}

// ---------------- flash attention, MFMA, online softmax (defer-max) ----------------
__global__ __launch_bounds__(256,2) void k_attn(const u16* __restrict__ qbf,
        const u16* __restrict__ kbf, const u16* __restrict__ vbf, u16* __restrict__ abf) {
  __shared__ alignas(16) u16 Qs[128][40];
  __shared__ alignas(16) u16 Ks[64][40];
  __shared__ alignas(16) u16 Vs[2][32][40];
  __shared__ alignas(16) u16 Ps[4][2][32][40];
  int tid = threadIdx.x, lane = tid & 63, wid = tid >> 6;
  int li = lane & 15, gr = lane >> 4;
  int h = blockIdx.y, n = blockIdx.z;
  int q0 = blockIdx.x*128;
  const u32* Qp32 = (const u32*)qbf + ((size_t)n*128 + h*16)*1296;
  const u32* Kp32 = (const u32*)kbf + ((size_t)n*128 + h*16)*1156;
  const u16* Vp = vbf + ((size_t)n*256 + h*32)*1156;
  #pragma unroll
  for (int j = 0; j < 8; j++) {
    int idx = tid + j*256, qq = idx >> 4, cp = idx & 15;
    int gq = q0 + qq;
    ((u32*)&Qs[qq][0])[cp] = (gq < 1296) ? Qp32[(size_t)cp*1296 + gq] : 0u;
  }
  f4 z = {0.f,0.f,0.f,0.f};
  float mx[2] = {-1e30f, -1e30f}, ls[2] = {0.f, 0.f};
  f4 accO[2][2] = {{z,z},{z,z}};
  int wq = wid*32;
  int kdd = tid >> 2, kq = tid & 3;
  __syncthreads();
  for (int d0 = 0; d0 < 1156; d0 += 64) {
    {
      u32 kk[4];
      int gd = d0 + kdd;
      #pragma unroll
      for (int i = 0; i < 4; i++)
        kk[i] = (gd < 1156) ? Kp32[(size_t)(kq*4+i)*1156 + gd] : 0u;
      *(int4*)&Ks[kdd][SWC(kdd,kq)*8] = *(int4*)&kk[0];
    }
    #pragma unroll
    for (int j = 0; j < 4; j++) {
      int idx = tid + j*256, half = idx >> 9, rem = idx & 511;
      int cc = rem >> 4, dp = rem & 15;
      int gd = d0 + half*32 + dp*2; u32 v = 0;
      if (gd < 1156) v = *(const u32*)&Vp[(size_t)cc*1156 + gd];
      ((u32*)&Vs[half][cc][0])[dp] = v;
    }
    __syncthreads();
    bf8 ak[4], bq[2];
    #pragma unroll
    for (int dt=0;dt<4;dt++) { int r = dt*16+li; ak[dt] = *(bf8*)&Ks[r][SWC(r,gr)*8]; }
    #pragma unroll
    for (int qt=0;qt<2;qt++) bq[qt] = *(bf8*)&Qs[wq + qt*16 + li][8*gr];
    f4 s[2][4];
    #pragma unroll
    for (int qt=0;qt<2;qt++)
      #pragma unroll
      for (int dt=0;dt<4;dt++)
        s[qt][dt] = MFMA(ak[dt], bq[qt], z);
    bool tail = (d0 + 64 > 1156);
    #pragma unroll
    for (int qt=0;qt<2;qt++) {
      if (tail) {
        #pragma unroll
        for (int dt=0;dt<4;dt++)
          #pragma unroll
          for (int j=0;j<4;j++)
            if (d0 + dt*16 + gr*4 + j >= 1156) s[qt][dt][j] = -1e30f;
      }
      float tm = -1e30f;
      #pragma unroll
      for (int dt=0;dt<4;dt++)
        #pragma unroll
        for (int j=0;j<4;j++) tm = fmaxf(tm, s[qt][dt][j]);
      tm = fmaxf(tm, __shfl_xor(tm, 16));
      tm = fmaxf(tm, __shfl_xor(tm, 32));
      if (__any(tm > mx[qt] + 8.f)) {
        float nm = fmaxf(mx[qt], tm);
        float corr = __expf(mx[qt] - nm);
        mx[qt] = nm;
        ls[qt] *= corr;
        accO[0][qt] *= corr; accO[1][qt] *= corr;
      }
      float rs = 0.f;
      #pragma unroll
      for (int dt=0;dt<4;dt++)
        #pragma unroll
        for (int j=0;j<4;j++) {
          float e = __expf(s[qt][dt][j] - mx[qt]);
          s[qt][dt][j] = e; rs += e;
        }
      rs += __shfl_xor(rs, 16); rs += __shfl_xor(rs, 32);
      ls[qt] += rs;
      #pragma unroll
      for (int dt=0;dt<4;dt++) {
        u32 lo_ = cvtpk(s[qt][dt][0], s[qt][dt][1]);
        u32 hi_ = cvtpk(s[qt][dt][2], s[qt][dt][3]);
        u64 pk = (u64)lo_ | ((u64)hi_ << 32);
        *(u64*)&Ps[wid][dt>>1][qt*16 + li][(dt&1)*16 + gr*4] = pk;
      }
    }
    #pragma unroll
    for (int kt=0;kt<2;kt++) {
      bf8 av0 = *(bf8*)&Vs[kt][li][8*gr];
      bf8 av1 = *(bf8*)&Vs[kt][16 + li][8*gr];
      bf8 bp0 = *(bf8*)&Ps[wid][kt][li][8*gr];
      bf8 bp1 = *(bf8*)&Ps[wid][kt][16 + li][8*gr];
      accO[0][0] = MFMA(av0, bp0, accO[0][0]);
      accO[0][1] = MFMA(av0, bp1, accO[0][1]);
      accO[1][0] = MFMA(av1, bp0, accO[1][0]);
      accO[1][1] = MFMA(av1, bp1, accO[1][1]);
    }
    __syncthreads();
  }
  u32* ab32 = (u32*)abf + (size_t)n*128*1296;
  #pragma unroll
  for (int qt=0;qt<2;qt++) {
    float inv = 1.f / ls[qt];
    #pragma unroll
    for (int mt=0;mt<2;mt++) {
      int cb = h*32 + mt*16 + gr*4;
      int gq = q0 + wq + qt*16 + li;
      if (gq < 1296) {
        ab32[(size_t)(cb>>1)*1296 + gq] = cvtpk(accO[mt][qt][0]*inv, accO[mt][qt][1]*inv);
        ab32[(size_t)((cb>>1)+1)*1296 + gq] = cvtpk(accO[mt][qt][2]*inv, accO[mt][qt][3]*inv);
      }
    }
  }
}

// ---------------- fused gates GEMM (i,g,o; K=512) + LSTM nonlinearity ----------------
__global__ __launch_bounds__(256,2) void k_gates(const u16* __restrict__ abf,
        const u16* __restrict__ xin, const u16* __restrict__ wg,
        const float* __restrict__ b_g, u16* __restrict__ hn) {
  __shared__ alignas(16) u16 Xs[128][40];
  __shared__ alignas(16) u16 Wg[3][64][40];
  int tid = threadIdx.x, lane = tid & 63, wid = tid >> 6;
  int li = lane & 15, gr = lane >> 4;
  int p0 = blockIdx.x*128, m0 = blockIdx.y*64, n = blockIdx.z;
  int pcol = tid & 127, rg = tid >> 7;
  int p = p0 + pcol;
  const u32* wg32 = (const u32*)wg;
  f4 z = {0.f,0.f,0.f,0.f};
  f4 acc[3][2][4];
  #pragma unroll
  for (int g=0;g<3;g++)
    #pragma unroll
    for (int mt=0;mt<2;mt++) { acc[g][mt][0]=z; acc[g][mt][1]=z; acc[g][mt][2]=z; acc[g][mt][3]=z; }
  int wm = (wid & 1)*32, wp = (wid >> 1)*64;
  for (int k0 = 0; k0 < 512; k0 += 32) {
    const u32* src32 = (const u32*)((k0 < 256) ? abf : xin)
        + (size_t)n*128*1296 + (size_t)((k0 & 255)>>1)*1296;
    u32 rx[8];
    #pragma unroll
    for (int j = 0; j < 8; j++) {
      int rp = rg*8 + j;
      rx[j] = (p < 1296) ? src32[(size_t)rp*1296 + p] : 0u;
    }
    *(int4*)&Xs[pcol][SWC(pcol,2*rg)*8]   = *(int4*)&rx[0];
    *(int4*)&Xs[pcol][SWC(pcol,2*rg+1)*8] = *(int4*)&rx[4];
    #pragma unroll
    for (int j = 0; j < 3; j++) {
      int sid = tid + j*256;
      int rid = sid >> 2, q = sid & 3;
      int g = rid >> 6, mm = rid & 63;
      const u32* wsrc = wg32 + (size_t)g*65536 + (size_t)(m0+mm)*256 + (k0>>1) + q*4;
      int4 w4 = *(const int4*)wsrc;
      *(int4*)&Wg[g][mm][SWC(mm,q)*8] = w4;
    }
    __syncthreads();
    bf8 bx[4];
    #pragma unroll
    for (int pt=0;pt<4;pt++) { int r = wp+pt*16+li; bx[pt] = *(bf8*)&Xs[r][SWC(r,gr)*8]; }
    #pragma unroll
    for (int g=0;g<3;g++)
      #pragma unroll
      for (int mt=0;mt<2;mt++) {
        int r = wm+mt*16+li;
        bf8 af = *(bf8*)&Wg[g][r][SWC(r,gr)*8];
        #pragma unroll
        for (int pt=0;pt<4;pt++)
          acc[g][mt][pt] = MFMA(af, bx[pt], acc[g][mt][pt]);
      }
    __syncthreads();
  }
  u32* hn32 = (u32*)hn + (size_t)n*128*1296;
  #pragma unroll
  for (int mt=0;mt<2;mt++)
    #pragma unroll
    for (int pt=0;pt<4;pt++) {
      int rb = m0 + wm + mt*16 + gr*4;
      int pp = p0 + wp + pt*16 + li;
      if (pp < 1296) {
        float hv[4];
        #pragma unroll
        for (int j=0;j<4;j++) {
          float gi = acc[0][mt][pt][j] + b_g[rb+j];
          float gg = acc[1][mt][pt][j] + b_g[512 + rb+j];
          float go = acc[2][mt][pt][j] + b_g[768 + rb+j];
          hv[j] = sigm(go) * tanhf(sigm(gi) * tanhf(gg));
        }
        hn32[(size_t)(rb>>1)*1296 + pp] = cvtpk(hv[0], hv[1]);
        hn32[(size_t)((rb>>1)+1)*1296 + pp] = cvtpk(hv[2], hv[3]);
      }
    }
}

// ---------------- out GEMM: M=256,K=256 over hn (pair-interleaved), out fp32 -------
__global__ __launch_bounds__(256,2) void k_out(const u16* __restrict__ hn,
        const u16* __restrict__ wb, const float* __restrict__ bias,
        float* __restrict__ out) {
  __shared__ alignas(16) u16 Xs[128][40];
  __shared__ alignas(16) u16 Ws[128][40];
  int tid = threadIdx.x, lane = tid & 63, wid = tid >> 6;
  int li = lane & 15, gr = lane >> 4;
  int p0 = blockIdx.x*128, m0 = blockIdx.y*128, n = blockIdx.z;
  int pcol = tid & 127, rg = tid >> 7;
  int wrow = tid >> 1, wh = tid & 1;
  int p = p0 + pcol;
  const u32* src32 = (const u32*)hn + (size_t)n*128*1296;
  const u32* wb32 = (const u32*)wb;
  f4 z = {0.f,0.f,0.f,0.f};
  f4 acc[4][4];
  #pragma unroll
  for (int i=0;i<4;i++) { acc[i][0]=z; acc[i][1]=z; acc[i][2]=z; acc[i][3]=z; }
  int wm = (wid & 1)*64, wp = (wid >> 1)*64;
  for (int k0 = 0; k0 < 256; k0 += 32) {
    u32 rx[8];
    #pragma unroll
    for (int j = 0; j < 8; j++) {
      int rp = rg*8 + j;
      rx[j] = (p < 1296) ? src32[(size_t)((k0>>1) + rp)*1296 + p] : 0u;
    }
    const u32* wsrc = wb32 + (size_t)(m0+wrow)*128 + (k0>>1) + wh*8;
    int4 rwA = *(const int4*)wsrc, rwB = *(const int4*)(wsrc+4);
    *(int4*)&Xs[pcol][SWC(pcol,2*rg)*8]   = *(int4*)&rx[0];
    *(int4*)&Xs[pcol][SWC(pcol,2*rg+1)*8] = *(int4*)&rx[4];
    *(int4*)&Ws[wrow][SWC(wrow,2*wh)*8]   = rwA;
    *(int4*)&Ws[wrow][SWC(wrow,2*wh+1)*8] = rwB;
    __syncthreads();
    bf8 af[4], bx[4];
    #pragma unroll
    for (int mt=0;mt<4;mt++) { int r = wm+mt*16+li; af[mt] = *(bf8*)&Ws[r][SWC(r,gr)*8]; }
    #pragma unroll
    for (int pt=0;pt<4;pt++) { int r = wp+pt*16+li; bx[pt] = *(bf8*)&Xs[r][SWC(r,gr)*8]; }
    #pragma unroll
    for (int mt=0;mt<4;mt++)
      #pragma unroll
      for (int pt=0;pt<4;pt++)
        acc[mt][pt] = MFMA(af[mt], bx[pt], acc[mt][pt]);
    __syncthreads();
  }
  #pragma unroll
  for (int mt=0;mt<4;mt++)
    #pragma unroll
    for (int pt=0;pt<4;pt++)
      #pragma unroll
      for (int j=0;j<4;j++) {
        int m = m0 + wm + mt*16 + gr*4 + j;
        int pp = p0 + wp + pt*16 + li;
        if (pp < 1296) out[((size_t)n*256 + m)*1296 + pp] = acc[mt][pt][j] + bias[m];
      }
}

extern "C" void kernel_launch(void* const* d_in, const int* in_sizes, int n_in,
                              void* d_out, int out_size, void* d_ws, size_t ws_size,
                              hipStream_t stream) {
  const float* x     = (const float*)d_in[0];
  const float* w_in  = (const float*)d_in[1];
  const float* b_in  = (const float*)d_in[2];
  const float* w_qx  = (const float*)d_in[3];
  const float* w_kx  = (const float*)d_in[5];
  const float* w_vx  = (const float*)d_in[7];
  const float* w_ga  = (const float*)d_in[9];
  const float* b_g   = (const float*)d_in[10];
  const float* w_gx  = (const float*)d_in[11];
  const float* w_out = (const float*)d_in[13];
  const float* b_out = (const float*)d_in[14];
  float* out = (float*)d_out;

  u16* ws = (u16*)d_ws;
  size_t o = 0;
  u16* xin_bf = ws + o; o += 2654208;
  u16* qbuf   = ws + o; o += 2654208;
  u16* kbuf   = ws + o; o += 2367488;
  u16* vbuf   = ws + o; o += 2367488;
  u16* abuf   = ws + o; o += 2654208;
  u16* hnb    = ws + o; o += 2654208;
  u16* wqT    = ws + o; o += 589824;
  u16* wkT    = ws + o; o += 589824;
  u16* wvT    = ws + o; o += 589824;
  u16* wgT    = ws + o; o += 393216;
  u16* winb   = ws + o; o += 32768;
  u16* woutb  = ws + o; o += 65536;

  k_prep<<<dim3(2304,5), 256, 0, stream>>>(w_in, w_out, w_qx, w_kx, w_vx,
                                           w_ga, w_gx, winb, woutb, wqT, wkT, wvT, wgT);

  k_xin  <<<dim3(11,2,8), 256, 0, stream>>>(x, winb, b_in, xin_bf);
  k_conv3<<<dim3(16,4,8), 256, 0, stream>>>(xin_bf, wqT, wkT, wvT, qbuf, kbuf, vbuf);
  k_attn <<<dim3(11,8,8), 256, 0, stream>>>(qbuf, kbuf, vbuf, abuf);
  k_gates<<<dim3(11,4,8), 256, 0, stream>>>(abuf, xin_bf, wgT, b_g, hnb);
  k_out  <<<dim3(11,2,8), 256, 0, stream>>>(hnb, woutb, b_out, out);
}